// Round 15
// baseline (1652.010 us; speedup 1.0000x reference)
//
#include <hip/hip_runtime.h>
#include <hip/hip_bf16.h>
#include <utility>

#define KVOL 27

using bf16 = __hip_bfloat16;
typedef __attribute__((ext_vector_type(8))) short short8;
typedef __attribute__((ext_vector_type(4))) short short4v;
typedef __attribute__((ext_vector_type(4))) float f32x4;
typedef __attribute__((ext_vector_type(4))) int int4v;

// async global->LDS 16B DMA; lds base is wave-uniform, HW writes lane i at base+i*16
__device__ __forceinline__ void async16(const void* g, void* l) {
    __builtin_amdgcn_global_load_lds(
        (const __attribute__((address_space(1))) void*)g,
        (__attribute__((address_space(3))) void*)l, 16, 0, 0);
}

template <class F, int... Is>
__device__ __forceinline__ void static_for_impl(F&& f, std::integer_sequence<int, Is...>) {
    (f(std::integral_constant<int, Is>{}), ...);
}
template <int N, class F>
__device__ __forceinline__ void static_for(F&& f) {
    static_for_impl(static_cast<F&&>(f), std::make_integer_sequence<int, N>{});
}

// vmcnt immediate guaranteeing stageA(t) complete (R3-proven form).
template <int NT, int D, int BR, int NI, int NB>
constexpr int waitA(int t) {
    int s = ((t + D < NT) ? NI : 0);
    if (t < D) {
        for (int j = 0; j < t; ++j)
            s += ((j + D < NT) ? NI : 0) + ((j + BR < NT) ? NB : 0);
    } else {
        s += ((t - D + BR < NT) ? NB : 0);
        for (int j = t - D + 1; j < t; ++j)
            s += ((j + D < NT) ? NI : 0) + ((j + BR < NT) ? NB : 0);
    }
    return s;
}

// ---------------- grid barrier (device-scope, one counter per use) -------
// __syncthreads drains this block's stores (vmcnt(0) before s_barrier);
// AGENT release add writes back this XCD's L2; acquire poll invalidates.
__device__ __forceinline__ void grid_barrier(int* ctr, int nblk) {
    __syncthreads();
    if (threadIdx.x == 0) {
        __hip_atomic_fetch_add(ctr, 1, __ATOMIC_RELEASE, __HIP_MEMORY_SCOPE_AGENT);
        int v;
        do {
            __builtin_amdgcn_s_sleep(2);
            v = __hip_atomic_load(ctr, __ATOMIC_ACQUIRE, __HIP_MEMORY_SCOPE_AGENT);
        } while (v < nblk);
    }
    __syncthreads();
}

// ---------------- fused prep: cvt (16ch) + mnc x4 + pack + zero page/ctr --
struct PackJobs {
    const float* W[10];
    bf16* Wp[10];
    int cin[10];
    int cout[10];
    int kvol[10];
    int start[11];
};

struct PrepArgs {
    const float* feat; bf16* featb; int n_cvt;          // N0*4 threads
    const int* nbr[4]; const int* mask[4]; int* mnc[4];
    int mnc_start[5];                                   // prefix, units of 4 ints
    PackJobs pj; int n_pack;
    int* zp;
    int* ctr;                                           // 7*16 ints, zeroed here
};

__global__ __launch_bounds__(256) void prep_all_kernel(PrepArgs P) {
    if (blockIdx.x == 0 && threadIdx.x < 8) {
        int4v z = {0, 0, 0, 0};
        reinterpret_cast<int4v*>(P.zp)[threadIdx.x] = z;  // 128B zero page
    }
    if (blockIdx.x == 0 && threadIdx.x >= 16 && threadIdx.x < 128)
        P.ctr[threadIdx.x - 16] = 0;                      // barrier counters
    int T = blockIdx.x * 256 + threadIdx.x;

    // --- job 1: fp32 -> bf16 convert, native 16ch (4 elems/thread) ---
    if (T < P.n_cvt) {
        const int row = T >> 2;
        const int c4 = (T & 3) * 4;
        const float4 v = *reinterpret_cast<const float4*>(P.feat + (size_t)row * 16 + c4);
        short4v o;
        bf16 b0 = __float2bfloat16(v.x); o.x = *reinterpret_cast<short*>(&b0);
        bf16 b1 = __float2bfloat16(v.y); o.y = *reinterpret_cast<short*>(&b1);
        bf16 b2 = __float2bfloat16(v.z); o.z = *reinterpret_cast<short*>(&b2);
        bf16 b3 = __float2bfloat16(v.w); o.w = *reinterpret_cast<short*>(&b3);
        *reinterpret_cast<short4v*>(P.featb + (size_t)row * 16 + c4) = o;
        return;
    }
    T -= P.n_cvt;

    // --- job 2: mnc compress (4 ints/thread) ---
    if (T < P.mnc_start[4]) {
        int tb = 3;
#pragma unroll
        for (int q = 2; q >= 0; --q) if (T < P.mnc_start[q + 1]) tb = q;
        const int off = (T - P.mnc_start[tb]) * 4;
        const int4v nb = *reinterpret_cast<const int4v*>(P.nbr[tb] + off);
        const int4v mk = *reinterpret_cast<const int4v*>(P.mask[tb] + off);
        int4v r;
        r.x = mk.x ? nb.x : -1;
        r.y = mk.y ? nb.y : -1;
        r.z = mk.z ? nb.z : -1;
        r.w = mk.w ? nb.w : -1;
        *reinterpret_cast<int4v*>(P.mnc[tb] + off) = r;
        return;
    }
    T -= P.mnc_start[4];

    // --- job 3: weight pack ---
    if (T < P.n_pack) {
        const PackJobs& J = P.pj;
        int jb = 9;
#pragma unroll
        for (int q = 8; q >= 0; --q) if (T < J.start[q + 1]) jb = q;
        const int u = T - J.start[jb];
        const int CIN = J.cin[jb], COUT = J.cout[jb], KV = J.kvol[jb];
        const int CINP = CIN < 32 ? 32 : CIN;
        const int NCH = CINP / 32;
        const int e = u & 7;
        const int lane = (u >> 3) & 63;
        int rest = u >> 9;
        const int c = rest % NCH; rest /= NCH;
        const int k = rest % KV;
        const int ct = rest / KV;
        const int cout = ct * 16 + (lane & 15);
        const int cin = c * 32 + (lane >> 4) * 8 + e;
        const float v = (cin < CIN) ? J.W[jb][((size_t)k * CIN + cin) * COUT + cout] : 0.f;
        J.Wp[jb][u] = __float2bfloat16(v);
    }
}

// ---------------- sparse conv body (R14-proven, unchanged math) -----------
template <int CIN, int COUT, int CTW, int RT, int WPB, int D, int BR, bool OUT_F32, int FM>
__device__ __forceinline__ void conv_body(
    const bf16* __restrict__ x, const bf16* __restrict__ Wp,
    const int* __restrict__ mnc, const bf16* __restrict__ zp,
    void* __restrict__ outv, int Nout, char* smem_all, int bid,
    const bf16* __restrict__ xl, const bf16* __restrict__ Wm) {
    constexpr int CINP = (CIN < 32) ? 32 : CIN;
    constexpr int NCH = CINP / 32;
    constexpr int CH  = CIN / 8;
    constexpr int RPI = 64 / CH;
    constexpr int NI  = (RT * CIN) / 32;
    constexpr int NB  = CTW * NCH;
    constexpr int ROWS = RT * 16;
    constexpr int SLOT = ROWS * CIN * 2;
    constexpr int NS = D + 1;
    constexpr int TPL = (64 / ROWS) > 0 ? (64 / ROWS) : 1;
    constexpr int NL = (KVOL + TPL - 1) / TPL;
    constexpr int CTG = (COUT / 16) / CTW;
    constexpr int NT = KVOL;
    static_assert(!FM || (CTG == 1 && COUT == 32 && RT == 2), "FM path shape");

    const int w = threadIdx.x >> 6;
    if (w >= WPB) return;
    const int lane = threadIdx.x & 63;
    const int rg = bid / CTG;
    const int cg = bid - rg * CTG;
    const int rowbase = rg * (WPB * ROWS) + w * ROWS;
    if (rowbase >= Nout) return;
    const int r = lane & 15;
    const int g = lane >> 4;
    char* const sb = smem_all + w * (NS * SLOT);

    int mnw[NL];
    {
        const int row = rowbase + (lane % ROWS);
        const int rc = (row < Nout) ? row : (Nout - 1);
#pragma unroll
        for (int p = 0; p < NL; ++p) {
            const int k = p * TPL + (lane / ROWS);
            int v = -1;
            if (k < NT) {
                const int vv = mnc[(size_t)k * Nout + rc];
                v = (row < Nout) ? vv : -1;
            }
            mnw[p] = v;
        }
    }

    short8 bring[BR][CTW][NCH];
    auto loadB = [&](int t) {
#pragma unroll
        for (int cw = 0; cw < CTW; ++cw) {
            const int ct = cg * CTW + cw;
#pragma unroll
            for (int c = 0; c < NCH; ++c)
                bring[t % BR][cw][c] = *reinterpret_cast<const short8*>(
                    Wp + (((size_t)ct * KVOL + t) * NCH + c) * 512 + lane * 8);
        }
    };

    auto stageA = [&](int t) {
        char* const dst = sb + (t % NS) * SLOT;
        const int mw = mnw[t / TPL];
        const int tb = (t % TPL) * ROWS;
        const int rl0 = lane / CH;
        const int ch0 = lane % CH;
#pragma unroll
        for (int q = 0; q < NI; ++q) {
            const int rl = q * RPI + rl0;
            const int j = __builtin_amdgcn_ds_bpermute((tb + rl) * 4, mw);
            const int ch = (ch0 ^ (rl & (CH - 1))) * 8;
            const bf16* src = (j >= 0) ? (x + (size_t)j * CIN) : zp;
            async16(src + ch, dst + q * 1024);
        }
    };

    f32x4 acc[RT][CTW];
#pragma unroll
    for (int rt = 0; rt < RT; ++rt)
#pragma unroll
        for (int cw = 0; cw < CTW; ++cw) {
            f32x4 z = {0.f, 0.f, 0.f, 0.f};
            acc[rt][cw] = z;
        }

#pragma unroll
    for (int t = 0; t < BR; ++t) loadB(t);
#pragma unroll
    for (int t = 0; t < D; ++t) stageA(t);

    static_for<NT>([&](auto tc) {
        constexpr int t = decltype(tc)::value;
        asm volatile("s_waitcnt lgkmcnt(0)" ::: "memory");
        if constexpr (t + D < NT) stageA(t + D);
        constexpr int WN = waitA<NT, D, BR, NI, NB>(t);
        asm volatile("s_waitcnt vmcnt(%0)" :: "n"(WN) : "memory");
        const char* sp = sb + (t % NS) * SLOT;
        short8 af[RT][NCH];
#pragma unroll
        for (int rt = 0; rt < RT; ++rt)
#pragma unroll
            for (int c = 0; c < NCH; ++c) {
                const int R = rt * 16 + r;
                const int cc = c * 4 + g;
                short8 v = {0, 0, 0, 0, 0, 0, 0, 0};
                if (cc < CH) {
                    const int off = R * (CIN * 2) + ((cc ^ (R & (CH - 1))) * 16);
                    v = *reinterpret_cast<const short8*>(sp + off);
                }
                af[rt][c] = v;
            }
        __builtin_amdgcn_s_setprio(1);
#pragma unroll
        for (int c = 0; c < NCH; ++c)
#pragma unroll
            for (int cw = 0; cw < CTW; ++cw)
#pragma unroll
                for (int rt = 0; rt < RT; ++rt)
                    acc[rt][cw] = __builtin_amdgcn_mfma_f32_16x16x32_bf16(
                        af[rt][c], bring[t % BR][cw][c], acc[rt][cw], 0, 0, 0);
        __builtin_amdgcn_s_setprio(0);
        if constexpr (t + BR < NT) loadB(t + BR);
    });

    if constexpr (!FM) {
#pragma unroll
        for (int rt = 0; rt < RT; ++rt)
#pragma unroll
            for (int cw = 0; cw < CTW; ++cw) {
                const int col = (cg * CTW + cw) * 16 + r;
#pragma unroll
                for (int i = 0; i < 4; ++i) {
                    const int rowo = rowbase + rt * 16 + g * 4 + i;
                    if (rowo < Nout) {
                        const float v = fmaxf(acc[rt][cw][i], 0.f);
                        if (OUT_F32) ((float*)outv)[(size_t)rowo * COUT + col] = v;
                        else ((bf16*)outv)[(size_t)rowo * COUT + col] = __float2bfloat16(v);
                    }
                }
            }
    } else {
        // ---- fused merge epilogue (merge1 into up2), padded transpose ----
        asm volatile("s_waitcnt vmcnt(0) lgkmcnt(0)" ::: "memory");
        constexpr int TS = 40;
        bf16* sbT = (bf16*)sb;
#pragma unroll
        for (int rt = 0; rt < RT; ++rt)
#pragma unroll
            for (int cw = 0; cw < CTW; ++cw) {
                const int col = cw * 16 + r;
#pragma unroll
                for (int i = 0; i < 4; ++i) {
                    const int rowl = rt * 16 + g * 4 + i;
                    sbT[rowl * TS + col] = __float2bfloat16(fmaxf(acc[rt][cw][i], 0.f));
                }
            }
        short8 bm[2][2];
#pragma unroll
        for (int cw = 0; cw < 2; ++cw)
#pragma unroll
            for (int c = 0; c < 2; ++c)
                bm[cw][c] = *reinterpret_cast<const short8*>(Wm + ((size_t)(cw * 2 + c)) * 512 + lane * 8);
#pragma unroll
        for (int p = 0; p < 2; ++p) {
            const int arow = rowbase + p * 16 + r;
            const int arc = (arow < Nout) ? arow : (Nout - 1);
            short8 a0, a1;
            a0 = *reinterpret_cast<const short8*>(sbT + (p * 16 + r) * TS + g * 8);
            a1 = *reinterpret_cast<const short8*>(xl + (size_t)arc * 32 + g * 8);
            f32x4 am[2];
#pragma unroll
            for (int cw = 0; cw < 2; ++cw) {
                f32x4 z = {0.f, 0.f, 0.f, 0.f};
                am[cw] = __builtin_amdgcn_mfma_f32_16x16x32_bf16(a0, bm[cw][0], z, 0, 0, 0);
                am[cw] = __builtin_amdgcn_mfma_f32_16x16x32_bf16(a1, bm[cw][1], am[cw], 0, 0, 0);
            }
#pragma unroll
            for (int cw = 0; cw < 2; ++cw) {
                const int j = cw * 16 + r;
#pragma unroll
                for (int i = 0; i < 4; ++i) {
                    const int rowl = p * 16 + g * 4 + i;
                    const int row = rowbase + rowl;
                    if (row < Nout) {
                        const float m = fmaxf(am[cw][i], 0.f);
                        float red;
                        if (cw == 0) {
                            red = __bfloat162float(sbT[rowl * TS + 2 * j]) +
                                  __bfloat162float(sbT[rowl * TS + 2 * j + 1]);
                        } else {
                            const bf16* s = xl + (size_t)row * 32 + 2 * (j - 16);
                            red = __bfloat162float(s[0]) + __bfloat162float(s[1]);
                        }
                        ((bf16*)outv)[(size_t)row * 32 + j] = __float2bfloat16(m + red);
                    }
                }
            }
        }
    }
}

// ---------------- decoder merge body (2-wave virtual tile) ----------------
template <int C>
__device__ __forceinline__ void merge_body(
    const bf16* __restrict__ xb, const bf16* __restrict__ xl,
    const bf16* __restrict__ Wmp, bf16* __restrict__ out, int N, int vb) {
    constexpr int NCH = 2 * C / 32;
    constexpr int CTW = 2;
    constexpr int CTG = (C / 16) / CTW;

    const int w = threadIdx.x >> 6;
    const int lane = threadIdx.x & 63;
    const int wid = vb * 2 + w;
    const int rg = wid / CTG;
    const int cg = wid - rg * CTG;
    const int rowbase = rg * 16;
    if (rowbase >= N) return;
    const int r = lane & 15;
    const int g = lane >> 4;

    short8 a[NCH];
    const int arow = (rowbase + r < N) ? (rowbase + r) : (N - 1);
#pragma unroll
    for (int c = 0; c < NCH; ++c) {
        const int kbase = c * 32 + g * 8;
        const bf16* src = (kbase < C) ? (xb + (size_t)arow * C + kbase)
                                      : (xl + (size_t)arow * C + (kbase - C));
        a[c] = *reinterpret_cast<const short8*>(src);
    }

    f32x4 acc[CTW];
#pragma unroll
    for (int cw = 0; cw < CTW; ++cw) {
        f32x4 z = {0.f, 0.f, 0.f, 0.f};
        acc[cw] = z;
#pragma unroll
        for (int c = 0; c < NCH; ++c) {
            const size_t off = ((size_t)(cg * CTW + cw) * NCH + c) * 512 + lane * 8;
            const short8 b = *reinterpret_cast<const short8*>(Wmp + off);
            acc[cw] = __builtin_amdgcn_mfma_f32_16x16x32_bf16(a[c], b, acc[cw], 0, 0, 0);
        }
    }

#pragma unroll
    for (int cw = 0; cw < CTW; ++cw) {
        const int j = (cg * CTW + cw) * 16 + r;
#pragma unroll
        for (int i = 0; i < 4; ++i) {
            const int row = rowbase + g * 4 + i;
            if (row < N) {
                const float m = fmaxf(acc[cw][i], 0.f);
                const bf16* src = (2 * j < C) ? (xb + (size_t)row * C + 2 * j)
                                              : (xl + (size_t)row * C + (2 * j - C));
                const float red = __bfloat162float(src[0]) + __bfloat162float(src[1]);
                out[(size_t)row * C + j] = __float2bfloat16(m + red);
            }
        }
    }
}

// ---------------- persistent mega-kernel: all 8 stages, 7 grid barriers ---
struct MegaArgs {
    const bf16* featb;
    bf16 *x0, *e1, *xd, *e2, *xl2, *m2, *xl1, *m1;
    float* outp;
    const bf16 *Wp_in, *Wp_enc1, *Wp_down, *Wp_enc2, *Wp_lat2, *Wp_up2, *Wp_lat1, *Wp_up1, *Wmp2, *Wmp1;
    const int *mnc0, *mnc1, *mncd, *mncu;
    const bf16* zp;
    int* ctr;               // 7 counters, stride 16 ints
    int N0, N1;
};

__device__ __forceinline__ int ctiles(int Nout, int BROWS, int CTG) {
    return ((Nout + BROWS - 1) / BROWS) * CTG;
}

__global__ __launch_bounds__(128, 2) void mega_kernel(MegaArgs M) {
    __shared__ __align__(16) char smem[32768];
    const int GB = gridDim.x;
    const int N0 = M.N0, N1 = M.N1;

    // S0: conv_input (CIN16)
    for (int vb = blockIdx.x, T = ctiles(N0, 128, 1); vb < T; vb += GB)
        conv_body<16, 32, 2, 4, 2, 3, 4, false, 0>(M.featb, M.Wp_in, M.mnc0, M.zp, M.x0, N0, smem, vb, nullptr, nullptr);
    grid_barrier(M.ctr + 0 * 16, GB);

    // S1: enc1
    for (int vb = blockIdx.x, T = ctiles(N0, 128, 1); vb < T; vb += GB)
        conv_body<32, 32, 2, 4, 2, 3, 4, false, 0>(M.x0, M.Wp_enc1, M.mnc0, M.zp, M.e1, N0, smem, vb, nullptr, nullptr);
    grid_barrier(M.ctr + 1 * 16, GB);

    // S2: down (WPB2/RT1) + lat1 (independent; both read e1)
    for (int vb = blockIdx.x, T = ctiles(N1, 32, 2); vb < T; vb += GB)
        conv_body<32, 64, 2, 1, 2, 3, 4, false, 0>(M.e1, M.Wp_down, M.mncd, M.zp, M.xd, N1, smem, vb, nullptr, nullptr);
    for (int vb = blockIdx.x, T = ctiles(N0, 128, 1); vb < T; vb += GB)
        conv_body<32, 32, 2, 4, 2, 3, 4, false, 0>(M.e1, M.Wp_lat1, M.mnc0, M.zp, M.xl1, N0, smem, vb, nullptr, nullptr);
    grid_barrier(M.ctr + 2 * 16, GB);

    // S3: enc2
    for (int vb = blockIdx.x, T = ctiles(N1, 64, 2); vb < T; vb += GB)
        conv_body<64, 64, 2, 2, 2, 3, 4, false, 0>(M.xd, M.Wp_enc2, M.mnc1, M.zp, M.e2, N1, smem, vb, nullptr, nullptr);
    grid_barrier(M.ctr + 3 * 16, GB);

    // S4: lat2
    for (int vb = blockIdx.x, T = ctiles(N1, 64, 2); vb < T; vb += GB)
        conv_body<64, 64, 2, 2, 2, 3, 4, false, 0>(M.e2, M.Wp_lat2, M.mnc1, M.zp, M.xl2, N1, smem, vb, nullptr, nullptr);
    grid_barrier(M.ctr + 4 * 16, GB);

    // S5: merge2 (2-wave virtual tiles)
    {
        const int waves = ((N1 + 15) / 16) * 2;
        const int T = (waves + 1) / 2;
        for (int vb = blockIdx.x; vb < T; vb += GB)
            merge_body<64>(M.e2, M.xl2, M.Wmp2, M.m2, N1, vb);
    }
    grid_barrier(M.ctr + 5 * 16, GB);

    // S6: up2 + fused merge1 (writes m1; u2 never materialized)
    for (int vb = blockIdx.x, T = ctiles(N0, 64, 1); vb < T; vb += GB)
        conv_body<64, 32, 2, 2, 2, 2, 4, false, 1>(M.m2, M.Wp_up2, M.mncu, M.zp, M.m1, N0, smem, vb, M.xl1, M.Wmp1);
    grid_barrier(M.ctr + 6 * 16, GB);

    // S7: up1 -> fp32 output
    for (int vb = blockIdx.x, T = ctiles(N0, 128, 1); vb < T; vb += GB)
        conv_body<32, 32, 2, 4, 2, 3, 4, true, 0>(M.m1, M.Wp_up1, M.mnc0, M.zp, (void*)M.outp, N0, smem, vb, nullptr, nullptr);
}

static size_t align_up(size_t v) { return (v + 255) & ~(size_t)255; }

extern "C" void kernel_launch(void* const* d_in, const int* in_sizes, int n_in,
                              void* d_out, int out_size, void* d_ws, size_t ws_size,
                              hipStream_t stream) {
    const float* feat     = (const float*)d_in[0];
    const int*   nbr0     = (const int*)d_in[1];
    const int*   mask0    = (const int*)d_in[2];
    const int*   nbr1     = (const int*)d_in[3];
    const int*   mask1    = (const int*)d_in[4];
    const int*   nbr_down = (const int*)d_in[5];
    const int*   mask_down= (const int*)d_in[6];
    const int*   nbr_up   = (const int*)d_in[7];
    const int*   mask_up  = (const int*)d_in[8];
    const float* W_in     = (const float*)d_in[9];
    const float* W_enc1   = (const float*)d_in[10];
    const float* W_down   = (const float*)d_in[11];
    const float* W_enc2   = (const float*)d_in[12];
    const float* W_lat2   = (const float*)d_in[13];
    const float* W_merge2 = (const float*)d_in[14];
    const float* W_up2    = (const float*)d_in[15];
    const float* W_lat1   = (const float*)d_in[16];
    const float* W_merge1 = (const float*)d_in[17];
    const float* W_up1    = (const float*)d_in[18];

    const int N0 = in_sizes[0] / 16;
    const int N1 = in_sizes[3] / KVOL;

    char* p = (char*)d_ws;
    auto carve = [&](size_t bytes) { char* q = p; p += align_up(bytes); return q; };

    bf16* featb = (bf16*)carve((size_t)N0 * 16 * 2);   // native 16 ch
    bf16* x0    = (bf16*)carve((size_t)N0 * 32 * 2);
    bf16* e1    = (bf16*)carve((size_t)N0 * 32 * 2);
    bf16* xd    = (bf16*)carve((size_t)N1 * 64 * 2);
    bf16* e2    = (bf16*)carve((size_t)N1 * 64 * 2);
    bf16* xl2   = (bf16*)carve((size_t)N1 * 64 * 2);
    bf16* m2    = (bf16*)carve((size_t)N1 * 64 * 2);
    bf16* xl1   = (bf16*)carve((size_t)N0 * 32 * 2);
    bf16* m1    = (bf16*)carve((size_t)N0 * 32 * 2);
    bf16* zp    = (bf16*)carve(256);                   // zero page (128B used)
    int*  ctr   = (int*)carve(7 * 16 * sizeof(int));   // barrier counters

    int* mnc0 = (int*)carve((size_t)KVOL * N0 * 4);
    int* mnc1 = (int*)carve((size_t)KVOL * N1 * 4);
    int* mncd = (int*)carve((size_t)KVOL * N1 * 4);
    int* mncu = (int*)carve((size_t)KVOL * N0 * 4);

    const int sz_in   = 2 * KVOL * 1 * 512;
    const int sz_enc1 = 2 * KVOL * 1 * 512;
    const int sz_down = 4 * KVOL * 1 * 512;
    const int sz_enc2 = 4 * KVOL * 2 * 512;
    const int sz_lat2 = 4 * KVOL * 2 * 512;
    const int sz_up2  = 2 * KVOL * 2 * 512;
    const int sz_lat1 = 2 * KVOL * 1 * 512;
    const int sz_up1  = 2 * KVOL * 1 * 512;
    const int sz_wm2  = 4 * 1 * 4 * 512;
    const int sz_wm1  = 2 * 1 * 2 * 512;

    bf16* Wp_in   = (bf16*)carve((size_t)sz_in * 2);
    bf16* Wp_enc1 = (bf16*)carve((size_t)sz_enc1 * 2);
    bf16* Wp_down = (bf16*)carve((size_t)sz_down * 2);
    bf16* Wp_enc2 = (bf16*)carve((size_t)sz_enc2 * 2);
    bf16* Wp_lat2 = (bf16*)carve((size_t)sz_lat2 * 2);
    bf16* Wp_up2  = (bf16*)carve((size_t)sz_up2 * 2);
    bf16* Wp_lat1 = (bf16*)carve((size_t)sz_lat1 * 2);
    bf16* Wp_up1  = (bf16*)carve((size_t)sz_up1 * 2);
    bf16* Wmp2    = (bf16*)carve((size_t)sz_wm2 * 2);
    bf16* Wmp1    = (bf16*)carve((size_t)sz_wm1 * 2);

    // --- fused prep (cvt + mnc x4 + pack + zero page + ctr), one dispatch ---
    {
        PrepArgs P;
        P.feat = feat; P.featb = featb; P.n_cvt = N0 * 4;
        const int* nbs[4] = {nbr0, nbr1, nbr_down, nbr_up};
        const int* mks[4] = {mask0, mask1, mask_down, mask_up};
        int* mns[4] = {mnc0, mnc1, mncd, mncu};
        const int szs4[4] = {KVOL * N0 / 4, KVOL * N1 / 4, KVOL * N1 / 4, KVOL * N0 / 4};
        int macc = 0;
        for (int i = 0; i < 4; ++i) {
            P.nbr[i] = nbs[i]; P.mask[i] = mks[i]; P.mnc[i] = mns[i];
            P.mnc_start[i] = macc; macc += szs4[i];
        }
        P.mnc_start[4] = macc;

        const float* Ws[10] = {W_in, W_enc1, W_down, W_enc2, W_lat2, W_up2, W_lat1, W_up1, W_merge2, W_merge1};
        bf16* Wps[10] = {Wp_in, Wp_enc1, Wp_down, Wp_enc2, Wp_lat2, Wp_up2, Wp_lat1, Wp_up1, Wmp2, Wmp1};
        const int cins[10]  = {16, 32, 32, 64, 64, 64, 32, 32, 128, 64};
        const int couts[10] = {32, 32, 64, 64, 64, 32, 32, 32, 64, 32};
        const int kvs[10]   = {KVOL, KVOL, KVOL, KVOL, KVOL, KVOL, KVOL, KVOL, 1, 1};
        const int szs[10]   = {sz_in, sz_enc1, sz_down, sz_enc2, sz_lat2, sz_up2, sz_lat1, sz_up1, sz_wm2, sz_wm1};
        int acc = 0;
        for (int i = 0; i < 10; ++i) {
            P.pj.W[i] = Ws[i]; P.pj.Wp[i] = Wps[i];
            P.pj.cin[i] = cins[i]; P.pj.cout[i] = couts[i]; P.pj.kvol[i] = kvs[i];
            P.pj.start[i] = acc; acc += szs[i];
        }
        P.pj.start[10] = acc;
        P.n_pack = acc;
        P.zp = (int*)zp;
        P.ctr = ctr;

        const int total = P.n_cvt + macc + acc;
        prep_all_kernel<<<(total + 255) / 256, 256, 0, stream>>>(P);
    }

    // --- whole network: one persistent kernel, 7 grid barriers ---
    // Residency: 1024 blocks x 128 thr; LDS 32KB -> 4 blocks/CU (128KB<=160);
    // __launch_bounds__(128,2) caps VGPR<=256 -> >=8 waves/CU = 4 blocks. OK.
    {
        MegaArgs M;
        M.featb = featb; M.x0 = x0; M.e1 = e1; M.xd = xd; M.e2 = e2;
        M.xl2 = xl2; M.m2 = m2; M.xl1 = xl1; M.m1 = m1; M.outp = (float*)d_out;
        M.Wp_in = Wp_in; M.Wp_enc1 = Wp_enc1; M.Wp_down = Wp_down;
        M.Wp_enc2 = Wp_enc2; M.Wp_lat2 = Wp_lat2; M.Wp_up2 = Wp_up2;
        M.Wp_lat1 = Wp_lat1; M.Wp_up1 = Wp_up1; M.Wmp2 = Wmp2; M.Wmp1 = Wmp1;
        M.mnc0 = mnc0; M.mnc1 = mnc1; M.mncd = mncd; M.mncu = mncu;
        M.zp = zp; M.ctr = ctr; M.N0 = N0; M.N1 = N1;
        mega_kernel<<<1024, 128, 0, stream>>>(M);
    }
}

// Round 16
// 177.879 us; speedup vs baseline: 9.2873x; 9.2873x over previous
//
#include <hip/hip_runtime.h>
#include <hip/hip_bf16.h>
#include <utility>

#define KVOL 27

using bf16 = __hip_bfloat16;
typedef __attribute__((ext_vector_type(8))) short short8;
typedef __attribute__((ext_vector_type(4))) short short4v;
typedef __attribute__((ext_vector_type(4))) float f32x4;
typedef __attribute__((ext_vector_type(4))) int int4v;

// async global->LDS 16B DMA; lds base is wave-uniform, HW writes lane i at base+i*16
__device__ __forceinline__ void async16(const void* g, void* l) {
    __builtin_amdgcn_global_load_lds(
        (const __attribute__((address_space(1))) void*)g,
        (__attribute__((address_space(3))) void*)l, 16, 0, 0);
}

template <class F, int... Is>
__device__ __forceinline__ void static_for_impl(F&& f, std::integer_sequence<int, Is...>) {
    (f(std::integral_constant<int, Is>{}), ...);
}
template <int N, class F>
__device__ __forceinline__ void static_for(F&& f) {
    static_for_impl(static_cast<F&&>(f), std::make_integer_sequence<int, N>{});
}

// vmcnt immediate guaranteeing stageA(t) complete (R3-proven form; the
// prologue branch is the order-robust lower bound on ops younger than SA(t)).
template <int NT, int D, int BR, int NI, int NB>
constexpr int waitA(int t) {
    int s = ((t + D < NT) ? NI : 0);            // SA(t+D), issued before the wait
    if (t < D) {
        for (int j = 0; j < t; ++j)
            s += ((j + D < NT) ? NI : 0) + ((j + BR < NT) ? NB : 0);
    } else {
        s += ((t - D + BR < NT) ? NB : 0);      // loadB tail of SA(t)'s region
        for (int j = t - D + 1; j < t; ++j)
            s += ((j + D < NT) ? NI : 0) + ((j + BR < NT) ? NB : 0);
    }
    return s;
}

// ---------------- fused prep: cvt (16ch, no pad) + mnc x4 + pack + zero page
struct PackJobs {
    const float* W[10];
    bf16* Wp[10];
    int cin[10];
    int cout[10];
    int kvol[10];
    int start[11];
};

struct PrepArgs {
    const float* feat; bf16* featb; int n_cvt;          // N0*4 threads
    const int* nbr[4]; const int* mask[4]; int* mnc[4];
    int mnc_start[5];                                   // prefix, units of 4 ints
    PackJobs pj; int n_pack;
    int* zp;
};

__global__ __launch_bounds__(256) void prep_all_kernel(PrepArgs P) {
    if (blockIdx.x == 0 && threadIdx.x < 8) {
        int4v z = {0, 0, 0, 0};
        reinterpret_cast<int4v*>(P.zp)[threadIdx.x] = z;  // 128B zero page
    }
    int T = blockIdx.x * 256 + threadIdx.x;

    // --- job 1: fp32 -> bf16 convert, native 16ch (4 elems/thread) ---
    if (T < P.n_cvt) {
        const int row = T >> 2;
        const int c4 = (T & 3) * 4;
        const float4 v = *reinterpret_cast<const float4*>(P.feat + (size_t)row * 16 + c4);
        short4v o;
        bf16 b0 = __float2bfloat16(v.x); o.x = *reinterpret_cast<short*>(&b0);
        bf16 b1 = __float2bfloat16(v.y); o.y = *reinterpret_cast<short*>(&b1);
        bf16 b2 = __float2bfloat16(v.z); o.z = *reinterpret_cast<short*>(&b2);
        bf16 b3 = __float2bfloat16(v.w); o.w = *reinterpret_cast<short*>(&b3);
        *reinterpret_cast<short4v*>(P.featb + (size_t)row * 16 + c4) = o;
        return;
    }
    T -= P.n_cvt;

    // --- job 2: mnc compress (4 ints/thread) ---
    if (T < P.mnc_start[4]) {
        int tb = 3;
#pragma unroll
        for (int q = 2; q >= 0; --q) if (T < P.mnc_start[q + 1]) tb = q;
        const int off = (T - P.mnc_start[tb]) * 4;
        const int4v nb = *reinterpret_cast<const int4v*>(P.nbr[tb] + off);
        const int4v mk = *reinterpret_cast<const int4v*>(P.mask[tb] + off);
        int4v r;
        r.x = mk.x ? nb.x : -1;
        r.y = mk.y ? nb.y : -1;
        r.z = mk.z ? nb.z : -1;
        r.w = mk.w ? nb.w : -1;
        *reinterpret_cast<int4v*>(P.mnc[tb] + off) = r;
        return;
    }
    T -= P.mnc_start[4];

    // --- job 3: weight pack ---
    if (T < P.n_pack) {
        const PackJobs& J = P.pj;
        int jb = 9;
#pragma unroll
        for (int q = 8; q >= 0; --q) if (T < J.start[q + 1]) jb = q;
        const int u = T - J.start[jb];
        const int CIN = J.cin[jb], COUT = J.cout[jb], KV = J.kvol[jb];
        const int CINP = CIN < 32 ? 32 : CIN;
        const int NCH = CINP / 32;
        const int e = u & 7;
        const int lane = (u >> 3) & 63;
        int rest = u >> 9;
        const int c = rest % NCH; rest /= NCH;
        const int k = rest % KV;
        const int ct = rest / KV;
        const int cout = ct * 16 + (lane & 15);
        const int cin = c * 32 + (lane >> 4) * 8 + e;
        const float v = (cin < CIN) ? J.W[jb][((size_t)k * CIN + cin) * COUT + cout] : 0.f;
        J.Wp[jb][u] = __float2bfloat16(v);
    }
}

// ---------------- sparse conv body: async-DMA staged, counted-vmcnt pipeline
// Wave owns RT*16 rows x (CTW*16) cols over all 27 taps. A staged via
// global_load_lds (whole-line mapping, XOR swizzle on the per-lane GLOBAL
// source; linear LDS dest). Masked taps -> zero page. D-deep tap pipeline,
// compile-time vmcnt counts; B ring (BR>=D) refilled at region TAIL.
// setprio(1) around the MFMA nest. No __syncthreads.
// CIN=16: native 32B rows (half the stage instrs); A-fragments for k>=16
// are zeroed in registers (exact: A=0 => zero contribution).
// FM=1 (requires CTG==1, COUT==32): fuse decoder merge into the epilogue.
template <int CIN, int COUT, int CTW, int RT, int WPB, int D, int BR, bool OUT_F32, int FM>
__device__ __forceinline__ void conv_body(
    const bf16* __restrict__ x, const bf16* __restrict__ Wp,
    const int* __restrict__ mnc, const bf16* __restrict__ zp,
    void* __restrict__ outv, int Nout, char* smem_all, int bid,
    const bf16* __restrict__ xl, const bf16* __restrict__ Wm) {
    constexpr int CINP = (CIN < 32) ? 32 : CIN;   // fragment K padding
    constexpr int NCH = CINP / 32;             // MFMA K-chunks
    constexpr int CH  = CIN / 8;               // real 16B chunks per row
    constexpr int RPI = 64 / CH;               // rows staged per instr
    constexpr int NI  = (RT * CIN) / 32;       // stage instrs per tap
    constexpr int NB  = CTW * NCH;             // B loads per tap
    constexpr int ROWS = RT * 16;
    constexpr int SLOT = ROWS * CIN * 2;       // bytes per tap tile
    constexpr int NS = D + 1;
    constexpr int TPL = (64 / ROWS) > 0 ? (64 / ROWS) : 1;  // taps per packed mnc load
    constexpr int NL = (KVOL + TPL - 1) / TPL;
    constexpr int CTG = (COUT / 16) / CTW;
    constexpr int NT = KVOL;
    static_assert(!FM || (CTG == 1 && COUT == 32 && RT == 2), "FM path shape");

    const int w = threadIdx.x >> 6;
    if (w >= WPB) return;                      // dual-dispatch: excess waves exit
    const int lane = threadIdx.x & 63;
    const int rg = bid / CTG;
    const int cg = bid - rg * CTG;
    const int rowbase = rg * (WPB * ROWS) + w * ROWS;
    if (rowbase >= Nout) return;
    const int r = lane & 15;
    const int g = lane >> 4;
    char* const sb = smem_all + w * (NS * SLOT);

    // packed mnc: load p covers taps p*TPL..p*TPL+TPL-1; lane = tp*ROWS + row
    int mnw[NL];
    {
        const int row = rowbase + (lane % ROWS);
        const int rc = (row < Nout) ? row : (Nout - 1);
#pragma unroll
        for (int p = 0; p < NL; ++p) {
            const int k = p * TPL + (lane / ROWS);
            int v = -1;
            if (k < NT) {
                const int vv = mnc[(size_t)k * Nout + rc];
                v = (row < Nout) ? vv : -1;
            }
            mnw[p] = v;
        }
    }

    short8 bring[BR][CTW][NCH];
    auto loadB = [&](int t) {
#pragma unroll
        for (int cw = 0; cw < CTW; ++cw) {
            const int ct = cg * CTW + cw;
#pragma unroll
            for (int c = 0; c < NCH; ++c)
                bring[t % BR][cw][c] = *reinterpret_cast<const short8*>(
                    Wp + (((size_t)ct * KVOL + t) * NCH + c) * 512 + lane * 8);
        }
    };

    auto stageA = [&](int t) {
        char* const dst = sb + (t % NS) * SLOT;
        const int mw = mnw[t / TPL];
        const int tb = (t % TPL) * ROWS;
        const int rl0 = lane / CH;             // row within stage instr
        const int ch0 = lane % CH;             // chunk within row
#pragma unroll
        for (int q = 0; q < NI; ++q) {
            const int rl = q * RPI + rl0;      // row within tile
            const int j = __builtin_amdgcn_ds_bpermute((tb + rl) * 4, mw);
            const int ch = (ch0 ^ (rl & (CH - 1))) * 8;        // XOR swizzle
            const bf16* src = (j >= 0) ? (x + (size_t)j * CIN) : zp;
            async16(src + ch, dst + q * 1024);
        }
    };

    f32x4 acc[RT][CTW];
#pragma unroll
    for (int rt = 0; rt < RT; ++rt)
#pragma unroll
        for (int cw = 0; cw < CTW; ++cw) {
            f32x4 z = {0.f, 0.f, 0.f, 0.f};
            acc[rt][cw] = z;
        }

    // prologue: BR B tiles first (older than all SA), then D A tiles
#pragma unroll
    for (int t = 0; t < BR; ++t) loadB(t);
#pragma unroll
    for (int t = 0; t < D; ++t) stageA(t);

    static_for<NT>([&](auto tc) {
        constexpr int t = decltype(tc)::value;
        // all prior ds_reads retired before their slot is re-DMA'd
        asm volatile("s_waitcnt lgkmcnt(0)" ::: "memory");
        if constexpr (t + D < NT) stageA(t + D);
        constexpr int WN = waitA<NT, D, BR, NI, NB>(t);
        asm volatile("s_waitcnt vmcnt(%0)" :: "n"(WN) : "memory");
        const char* sp = sb + (t % NS) * SLOT;
        short8 af[RT][NCH];
#pragma unroll
        for (int rt = 0; rt < RT; ++rt)
#pragma unroll
            for (int c = 0; c < NCH; ++c) {
                const int R = rt * 16 + r;
                const int cc = c * 4 + g;
                short8 v = {0, 0, 0, 0, 0, 0, 0, 0};
                if (cc < CH) {                 // compile-time true for CIN>=32
                    const int off = R * (CIN * 2) + ((cc ^ (R & (CH - 1))) * 16);
                    v = *reinterpret_cast<const short8*>(sp + off);
                }
                af[rt][c] = v;
            }
        __builtin_amdgcn_s_setprio(1);
#pragma unroll
        for (int c = 0; c < NCH; ++c)
#pragma unroll
            for (int cw = 0; cw < CTW; ++cw)
#pragma unroll
                for (int rt = 0; rt < RT; ++rt)
                    acc[rt][cw] = __builtin_amdgcn_mfma_f32_16x16x32_bf16(
                        af[rt][c], bring[t % BR][cw][c], acc[rt][cw], 0, 0, 0);
        __builtin_amdgcn_s_setprio(0);
        // ring refill AFTER last read of this slot (WAR, not RAW)
        if constexpr (t + BR < NT) loadB(t + BR);
    });

    if constexpr (!FM) {
        // epilogue: wave owns its tile outright
#pragma unroll
        for (int rt = 0; rt < RT; ++rt)
#pragma unroll
            for (int cw = 0; cw < CTW; ++cw) {
                const int col = (cg * CTW + cw) * 16 + r;
#pragma unroll
                for (int i = 0; i < 4; ++i) {
                    const int rowo = rowbase + rt * 16 + g * 4 + i;
                    if (rowo < Nout) {
                        const float v = fmaxf(acc[rt][cw][i], 0.f);
                        if (OUT_F32) ((float*)outv)[(size_t)rowo * COUT + col] = v;
                        else ((bf16*)outv)[(size_t)rowo * COUT + col] = __float2bfloat16(v);
                    }
                }
            }
    } else {
        // ---- fused merge epilogue (merge1 into up2) ----
        asm volatile("s_waitcnt vmcnt(0) lgkmcnt(0)" ::: "memory");
        // padded transpose buffer: stride 40 bf16 (80B) keeps 16B alignment
        // for the b128 reads while stepping row bank-base by 20 mod 32.
        constexpr int TS = 40;
        bf16* sbT = (bf16*)sb;
#pragma unroll
        for (int rt = 0; rt < RT; ++rt)
#pragma unroll
            for (int cw = 0; cw < CTW; ++cw) {
                const int col = cw * 16 + r;
#pragma unroll
                for (int i = 0; i < 4; ++i) {
                    const int rowl = rt * 16 + g * 4 + i;
                    sbT[rowl * TS + col] = __float2bfloat16(fmaxf(acc[rt][cw][i], 0.f));
                }
            }
        short8 bm[2][2];
#pragma unroll
        for (int cw = 0; cw < 2; ++cw)
#pragma unroll
            for (int c = 0; c < 2; ++c)
                bm[cw][c] = *reinterpret_cast<const short8*>(Wm + ((size_t)(cw * 2 + c)) * 512 + lane * 8);
#pragma unroll
        for (int p = 0; p < 2; ++p) {
            const int arow = rowbase + p * 16 + r;
            const int arc = (arow < Nout) ? arow : (Nout - 1);
            short8 a0, a1;
            a0 = *reinterpret_cast<const short8*>(sbT + (p * 16 + r) * TS + g * 8);
            a1 = *reinterpret_cast<const short8*>(xl + (size_t)arc * 32 + g * 8);
            f32x4 am[2];
#pragma unroll
            for (int cw = 0; cw < 2; ++cw) {
                f32x4 z = {0.f, 0.f, 0.f, 0.f};
                am[cw] = __builtin_amdgcn_mfma_f32_16x16x32_bf16(a0, bm[cw][0], z, 0, 0, 0);
                am[cw] = __builtin_amdgcn_mfma_f32_16x16x32_bf16(a1, bm[cw][1], am[cw], 0, 0, 0);
            }
#pragma unroll
            for (int cw = 0; cw < 2; ++cw) {
                const int j = cw * 16 + r;
#pragma unroll
                for (int i = 0; i < 4; ++i) {
                    const int rowl = p * 16 + g * 4 + i;
                    const int row = rowbase + rowl;
                    if (row < Nout) {
                        const float m = fmaxf(am[cw][i], 0.f);
                        float red;
                        if (cw == 0) {
                            red = __bfloat162float(sbT[rowl * TS + 2 * j]) +
                                  __bfloat162float(sbT[rowl * TS + 2 * j + 1]);
                        } else {
                            const bf16* s = xl + (size_t)row * 32 + 2 * (j - 16);
                            red = __bfloat162float(s[0]) + __bfloat162float(s[1]);
                        }
                        ((bf16*)outv)[(size_t)row * 32 + j] = __float2bfloat16(m + red);
                    }
                }
            }
        }
    }
}

template <int CIN, int COUT, int CTW, int RT, int WPB, int D, int BR, int MINW, bool OUT_F32, int FM>
__global__ __launch_bounds__(WPB * 64, MINW) void conv_async_kernel(
    const bf16* __restrict__ x, const bf16* __restrict__ Wp,
    const int* __restrict__ mnc, const bf16* __restrict__ zp,
    void* __restrict__ outv, int Nout,
    const bf16* __restrict__ xl, const bf16* __restrict__ Wm) {
    constexpr int LDSB = WPB * (D + 1) * RT * 16 * CIN * 2;
    __shared__ __align__(16) char smem[LDSB];
    conv_body<CIN, COUT, CTW, RT, WPB, D, BR, OUT_F32, FM>(x, Wp, mnc, zp, outv, Nout, smem, blockIdx.x, xl, Wm);
}

// dual dispatch: blocks [0,split) run conv A, [split,...) run conv B.
template <int CIN1, int COUT1, int CTW1, int RT1, int WPB1, int D1, int BR1, bool OF1,
          int CIN2, int COUT2, int CTW2, int RT2, int WPB2, int D2, int BR2, bool OF2, int MINW>
__global__ __launch_bounds__(256, MINW) void conv_dual_kernel(
    const bf16* __restrict__ x1, const bf16* __restrict__ Wp1, const int* __restrict__ mnc1,
    void* __restrict__ out1, int Nout1,
    const bf16* __restrict__ x2, const bf16* __restrict__ Wp2, const int* __restrict__ mnc2,
    void* __restrict__ out2, int Nout2,
    const bf16* __restrict__ zp, int split) {
    constexpr int L1 = WPB1 * (D1 + 1) * RT1 * 16 * CIN1 * 2;
    constexpr int L2 = WPB2 * (D2 + 1) * RT2 * 16 * CIN2 * 2;
    constexpr int LM = (L1 > L2) ? L1 : L2;
    __shared__ __align__(16) char smem[LM];
    if ((int)blockIdx.x < split)
        conv_body<CIN1, COUT1, CTW1, RT1, WPB1, D1, BR1, OF1, 0>(x1, Wp1, mnc1, zp, out1, Nout1, smem, blockIdx.x, nullptr, nullptr);
    else
        conv_body<CIN2, COUT2, CTW2, RT2, WPB2, D2, BR2, OF2, 0>(x2, Wp2, mnc2, zp, out2, Nout2, smem, blockIdx.x - split, nullptr, nullptr);
}

// ---------------- decoder merge via MFMA ----------------
template <int C>
__global__ __launch_bounds__(256) void merge_mfma_kernel(
    const bf16* __restrict__ xb, const bf16* __restrict__ xl,
    const bf16* __restrict__ Wmp, bf16* __restrict__ out, int N) {
    constexpr int NCH = 2 * C / 32;
    constexpr int CT = C / 16;
    constexpr int CTW = 2;
    constexpr int CTG = CT / CTW;

    const int wid = blockIdx.x * (blockDim.x >> 6) + (threadIdx.x >> 6);
    const int lane = threadIdx.x & 63;
    const int rg = wid / CTG;
    const int cg = wid - rg * CTG;
    const int rowbase = rg * 16;
    if (rowbase >= N) return;
    const int r = lane & 15;
    const int g = lane >> 4;

    short8 a[NCH];
    const int arow = (rowbase + r < N) ? (rowbase + r) : (N - 1);
#pragma unroll
    for (int c = 0; c < NCH; ++c) {
        const int kbase = c * 32 + g * 8;
        const bf16* src = (kbase < C) ? (xb + (size_t)arow * C + kbase)
                                      : (xl + (size_t)arow * C + (kbase - C));
        a[c] = *reinterpret_cast<const short8*>(src);
    }

    f32x4 acc[CTW];
#pragma unroll
    for (int cw = 0; cw < CTW; ++cw) {
        f32x4 z = {0.f, 0.f, 0.f, 0.f};
        acc[cw] = z;
#pragma unroll
        for (int c = 0; c < NCH; ++c) {
            const size_t off = ((size_t)(cg * CTW + cw) * NCH + c) * 512 + lane * 8;
            const short8 b = *reinterpret_cast<const short8*>(Wmp + off);
            acc[cw] = __builtin_amdgcn_mfma_f32_16x16x32_bf16(a[c], b, acc[cw], 0, 0, 0);
        }
    }

#pragma unroll
    for (int cw = 0; cw < CTW; ++cw) {
        const int j = (cg * CTW + cw) * 16 + r;
#pragma unroll
        for (int i = 0; i < 4; ++i) {
            const int row = rowbase + g * 4 + i;
            if (row < N) {
                const float m = fmaxf(acc[cw][i], 0.f);
                const bf16* src = (2 * j < C) ? (xb + (size_t)row * C + 2 * j)
                                              : (xl + (size_t)row * C + (2 * j - C));
                const float red = __bfloat162float(src[0]) + __bfloat162float(src[1]);
                out[(size_t)row * C + j] = __float2bfloat16(m + red);
            }
        }
    }
}

// ---------------- host ----------------
template <int CIN, int COUT, int CTW, int RT, int WPB, int D, int BR, int MINW, bool OF32>
static void launch_conv(const bf16* x, const bf16* Wp, const int* mnc, const bf16* zp,
                        void* out, int Nout, hipStream_t s) {
    constexpr int CTG = (COUT / 16) / CTW;
    constexpr int BROWS = WPB * RT * 16;
    const int RG = (Nout + BROWS - 1) / BROWS;
    conv_async_kernel<CIN, COUT, CTW, RT, WPB, D, BR, MINW, OF32, 0>
        <<<RG * CTG, WPB * 64, 0, s>>>(x, Wp, mnc, zp, out, Nout, nullptr, nullptr);
}

template <int C>
static void launch_merge(const bf16* xb, const bf16* xl, const bf16* Wmp,
                         bf16* out, int N, hipStream_t s) {
    constexpr int CTG = (C / 16) / 2;
    const int RG = (N + 15) / 16;
    const int waves = RG * CTG;
    const int blocks = (waves + 3) / 4;
    merge_mfma_kernel<C><<<blocks, 256, 0, s>>>(xb, xl, Wmp, out, N);
}

static size_t align_up(size_t v) { return (v + 255) & ~(size_t)255; }

extern "C" void kernel_launch(void* const* d_in, const int* in_sizes, int n_in,
                              void* d_out, int out_size, void* d_ws, size_t ws_size,
                              hipStream_t stream) {
    const float* feat     = (const float*)d_in[0];
    const int*   nbr0     = (const int*)d_in[1];
    const int*   mask0    = (const int*)d_in[2];
    const int*   nbr1     = (const int*)d_in[3];
    const int*   mask1    = (const int*)d_in[4];
    const int*   nbr_down = (const int*)d_in[5];
    const int*   mask_down= (const int*)d_in[6];
    const int*   nbr_up   = (const int*)d_in[7];
    const int*   mask_up  = (const int*)d_in[8];
    const float* W_in     = (const float*)d_in[9];
    const float* W_enc1   = (const float*)d_in[10];
    const float* W_down   = (const float*)d_in[11];
    const float* W_enc2   = (const float*)d_in[12];
    const float* W_lat2   = (const float*)d_in[13];
    const float* W_merge2 = (const float*)d_in[14];
    const float* W_up2    = (const float*)d_in[15];
    const float* W_lat1   = (const float*)d_in[16];
    const float* W_merge1 = (const float*)d_in[17];
    const float* W_up1    = (const float*)d_in[18];

    const int N0 = in_sizes[0] / 16;
    const int N1 = in_sizes[3] / KVOL;

    char* p = (char*)d_ws;
    auto carve = [&](size_t bytes) { char* q = p; p += align_up(bytes); return q; };

    bf16* featb = (bf16*)carve((size_t)N0 * 16 * 2);   // native 16 ch
    bf16* x0    = (bf16*)carve((size_t)N0 * 32 * 2);
    bf16* e1    = (bf16*)carve((size_t)N0 * 32 * 2);
    bf16* xd    = (bf16*)carve((size_t)N1 * 64 * 2);
    bf16* e2    = (bf16*)carve((size_t)N1 * 64 * 2);
    bf16* xl2   = (bf16*)carve((size_t)N1 * 64 * 2);
    bf16* m2    = (bf16*)carve((size_t)N1 * 64 * 2);
    bf16* xl1   = (bf16*)carve((size_t)N0 * 32 * 2);
    bf16* m1    = (bf16*)carve((size_t)N0 * 32 * 2);
    bf16* zp    = (bf16*)carve(256);                   // zero page (128B used)

    int* mnc0 = (int*)carve((size_t)KVOL * N0 * 4);
    int* mnc1 = (int*)carve((size_t)KVOL * N1 * 4);
    int* mncd = (int*)carve((size_t)KVOL * N1 * 4);
    int* mncu = (int*)carve((size_t)KVOL * N0 * 4);

    const int sz_in   = 2 * KVOL * 1 * 512;
    const int sz_enc1 = 2 * KVOL * 1 * 512;
    const int sz_down = 4 * KVOL * 1 * 512;
    const int sz_enc2 = 4 * KVOL * 2 * 512;
    const int sz_lat2 = 4 * KVOL * 2 * 512;
    const int sz_up2  = 2 * KVOL * 2 * 512;
    const int sz_lat1 = 2 * KVOL * 1 * 512;
    const int sz_up1  = 2 * KVOL * 1 * 512;
    const int sz_wm2  = 4 * 1 * 4 * 512;
    const int sz_wm1  = 2 * 1 * 2 * 512;

    bf16* Wp_in   = (bf16*)carve((size_t)sz_in * 2);
    bf16* Wp_enc1 = (bf16*)carve((size_t)sz_enc1 * 2);
    bf16* Wp_down = (bf16*)carve((size_t)sz_down * 2);
    bf16* Wp_enc2 = (bf16*)carve((size_t)sz_enc2 * 2);
    bf16* Wp_lat2 = (bf16*)carve((size_t)sz_lat2 * 2);
    bf16* Wp_up2  = (bf16*)carve((size_t)sz_up2 * 2);
    bf16* Wp_lat1 = (bf16*)carve((size_t)sz_lat1 * 2);
    bf16* Wp_up1  = (bf16*)carve((size_t)sz_up1 * 2);
    bf16* Wmp2    = (bf16*)carve((size_t)sz_wm2 * 2);
    bf16* Wmp1    = (bf16*)carve((size_t)sz_wm1 * 2);

    // --- fused prep (cvt + mnc x4 + pack + zero page), one dispatch ---
    {
        PrepArgs P;
        P.feat = feat; P.featb = featb; P.n_cvt = N0 * 4;
        const int* nbs[4] = {nbr0, nbr1, nbr_down, nbr_up};
        const int* mks[4] = {mask0, mask1, mask_down, mask_up};
        int* mns[4] = {mnc0, mnc1, mncd, mncu};
        const int szs4[4] = {KVOL * N0 / 4, KVOL * N1 / 4, KVOL * N1 / 4, KVOL * N0 / 4};
        int macc = 0;
        for (int i = 0; i < 4; ++i) {
            P.nbr[i] = nbs[i]; P.mask[i] = mks[i]; P.mnc[i] = mns[i];
            P.mnc_start[i] = macc; macc += szs4[i];
        }
        P.mnc_start[4] = macc;

        const float* Ws[10] = {W_in, W_enc1, W_down, W_enc2, W_lat2, W_up2, W_lat1, W_up1, W_merge2, W_merge1};
        bf16* Wps[10] = {Wp_in, Wp_enc1, Wp_down, Wp_enc2, Wp_lat2, Wp_up2, Wp_lat1, Wp_up1, Wmp2, Wmp1};
        const int cins[10]  = {16, 32, 32, 64, 64, 64, 32, 32, 128, 64};
        const int couts[10] = {32, 32, 64, 64, 64, 32, 32, 32, 64, 32};
        const int kvs[10]   = {KVOL, KVOL, KVOL, KVOL, KVOL, KVOL, KVOL, KVOL, 1, 1};
        const int szs[10]   = {sz_in, sz_enc1, sz_down, sz_enc2, sz_lat2, sz_up2, sz_lat1, sz_up1, sz_wm2, sz_wm1};
        int acc = 0;
        for (int i = 0; i < 10; ++i) {
            P.pj.W[i] = Ws[i]; P.pj.Wp[i] = Wps[i];
            P.pj.cin[i] = cins[i]; P.pj.cout[i] = couts[i]; P.pj.kvol[i] = kvs[i];
            P.pj.start[i] = acc; acc += szs[i];
        }
        P.pj.start[10] = acc;
        P.n_pack = acc;
        P.zp = (int*)zp;

        const int total = P.n_cvt + macc + acc;
        prep_all_kernel<<<(total + 255) / 256, 256, 0, stream>>>(P);
    }

    // --- network ---
    // conv_input: native CIN=16.  CIN32-N0 convs: WPB=2/RT=4/D=3/BR=4.
    // dual(down+lat1): down D=3/BR=4 (LM 32768, 5 blocks/CU).
    // enc2/lat2: WPB=2/RT=2.
    // up2+merge1 (FM): D=2 (LDS 24576 -> 6 blocks/CU, matches 6.1/CU grid).
    launch_conv<16, 32, 2, 4, 2, 3, 4, 2, false>(featb, Wp_in, mnc0, zp, x0, N0, stream);
    launch_conv<32, 32, 2, 4, 2, 3, 4, 2, false>(x0, Wp_enc1, mnc0, zp, e1, N0, stream);

    {
        // down: CIN32/COUT64/CTW2/RT1/WPB4/D3/BR4 -> CTG=2, BROWS=64
        const int g_down = ((N1 + 63) / 64) * 2;
        // lat1: CIN32/COUT32/CTW2/RT4/WPB2/D3/BR4 -> CTG=1, BROWS=128
        const int g_lat1 = (N0 + 127) / 128;
        conv_dual_kernel<32, 64, 2, 1, 4, 3, 4, false,
                         32, 32, 2, 4, 2, 3, 4, false, 2>
            <<<g_down + g_lat1, 256, 0, stream>>>(
                e1, Wp_down, mncd, xd, N1,
                e1, Wp_lat1, mnc0, xl1, N0,
                zp, g_down);
    }

    launch_conv<64, 64, 2, 2, 2, 3, 4, 1, false>(xd, Wp_enc2, mnc1, zp, e2, N1, stream);
    launch_conv<64, 64, 2, 2, 2, 3, 4, 1, false>(e2, Wp_lat2, mnc1, zp, xl2, N1, stream);
    launch_merge<64>(e2, xl2, Wmp2, m2, N1, stream);

    {
        // up2 + fused merge1: writes m1 directly (u2 never hits global)
        constexpr int BROWS = 2 * 2 * 16;   // WPB*RT*16 = 64
        const int RG = (N0 + BROWS - 1) / BROWS;
        conv_async_kernel<64, 32, 2, 2, 2, 2, 4, 2, false, 1>
            <<<RG, 128, 0, stream>>>(m2, Wp_up2, mncu, zp, m1, N0, xl1, Wmp1);
    }

    launch_conv<32, 32, 2, 4, 2, 3, 4, 2, true>(m1, Wp_up1, mnc0, zp, (float*)d_out, N0, stream);
}

// Round 17
// 175.504 us; speedup vs baseline: 9.4129x; 1.0135x over previous
//
#include <hip/hip_runtime.h>
#include <hip/hip_bf16.h>
#include <utility>

#define KVOL 27

using bf16 = __hip_bfloat16;
typedef __attribute__((ext_vector_type(8))) short short8;
typedef __attribute__((ext_vector_type(4))) short short4v;
typedef __attribute__((ext_vector_type(4))) float f32x4;
typedef __attribute__((ext_vector_type(4))) int int4v;

// async global->LDS 16B DMA; lds base is wave-uniform, HW writes lane i at base+i*16
__device__ __forceinline__ void async16(const void* g, void* l) {
    __builtin_amdgcn_global_load_lds(
        (const __attribute__((address_space(1))) void*)g,
        (__attribute__((address_space(3))) void*)l, 16, 0, 0);
}

template <class F, int... Is>
__device__ __forceinline__ void static_for_impl(F&& f, std::integer_sequence<int, Is...>) {
    (f(std::integral_constant<int, Is>{}), ...);
}
template <int N, class F>
__device__ __forceinline__ void static_for(F&& f) {
    static_for_impl(static_cast<F&&>(f), std::make_integer_sequence<int, N>{});
}

// vmcnt immediate guaranteeing stageA(t) complete (R3-proven form; the
// prologue branch is the order-robust lower bound on ops younger than SA(t)).
template <int NT, int D, int BR, int NI, int NB>
constexpr int waitA(int t) {
    int s = ((t + D < NT) ? NI : 0);            // SA(t+D), issued before the wait
    if (t < D) {
        for (int j = 0; j < t; ++j)
            s += ((j + D < NT) ? NI : 0) + ((j + BR < NT) ? NB : 0);
    } else {
        s += ((t - D + BR < NT) ? NB : 0);      // loadB tail of SA(t)'s region
        for (int j = t - D + 1; j < t; ++j)
            s += ((j + D < NT) ? NI : 0) + ((j + BR < NT) ? NB : 0);
    }
    return s;
}

// ---------------- fused prep: cvt (16ch, no pad) + mnc x4 + pack + zero page
struct PackJobs {
    const float* W[10];
    bf16* Wp[10];
    int cin[10];
    int cout[10];
    int kvol[10];
    int start[11];
};

struct PrepArgs {
    const float* feat; bf16* featb; int n_cvt;          // N0*4 threads
    const int* nbr[4]; const int* mask[4]; int* mnc[4];
    int mnc_start[5];                                   // prefix, units of 4 ints
    PackJobs pj; int n_pack;
    int* zp;
};

__global__ __launch_bounds__(256) void prep_all_kernel(PrepArgs P) {
    if (blockIdx.x == 0 && threadIdx.x < 8) {
        int4v z = {0, 0, 0, 0};
        reinterpret_cast<int4v*>(P.zp)[threadIdx.x] = z;  // 128B zero page
    }
    int T = blockIdx.x * 256 + threadIdx.x;

    // --- job 1: fp32 -> bf16 convert, native 16ch (4 elems/thread) ---
    if (T < P.n_cvt) {
        const int row = T >> 2;
        const int c4 = (T & 3) * 4;
        const float4 v = *reinterpret_cast<const float4*>(P.feat + (size_t)row * 16 + c4);
        short4v o;
        bf16 b0 = __float2bfloat16(v.x); o.x = *reinterpret_cast<short*>(&b0);
        bf16 b1 = __float2bfloat16(v.y); o.y = *reinterpret_cast<short*>(&b1);
        bf16 b2 = __float2bfloat16(v.z); o.z = *reinterpret_cast<short*>(&b2);
        bf16 b3 = __float2bfloat16(v.w); o.w = *reinterpret_cast<short*>(&b3);
        *reinterpret_cast<short4v*>(P.featb + (size_t)row * 16 + c4) = o;
        return;
    }
    T -= P.n_cvt;

    // --- job 2: mnc compress (4 ints/thread) ---
    if (T < P.mnc_start[4]) {
        int tb = 3;
#pragma unroll
        for (int q = 2; q >= 0; --q) if (T < P.mnc_start[q + 1]) tb = q;
        const int off = (T - P.mnc_start[tb]) * 4;
        const int4v nb = *reinterpret_cast<const int4v*>(P.nbr[tb] + off);
        const int4v mk = *reinterpret_cast<const int4v*>(P.mask[tb] + off);
        int4v r;
        r.x = mk.x ? nb.x : -1;
        r.y = mk.y ? nb.y : -1;
        r.z = mk.z ? nb.z : -1;
        r.w = mk.w ? nb.w : -1;
        *reinterpret_cast<int4v*>(P.mnc[tb] + off) = r;
        return;
    }
    T -= P.mnc_start[4];

    // --- job 3: weight pack ---
    if (T < P.n_pack) {
        const PackJobs& J = P.pj;
        int jb = 9;
#pragma unroll
        for (int q = 8; q >= 0; --q) if (T < J.start[q + 1]) jb = q;
        const int u = T - J.start[jb];
        const int CIN = J.cin[jb], COUT = J.cout[jb], KV = J.kvol[jb];
        const int CINP = CIN < 32 ? 32 : CIN;
        const int NCH = CINP / 32;
        const int e = u & 7;
        const int lane = (u >> 3) & 63;
        int rest = u >> 9;
        const int c = rest % NCH; rest /= NCH;
        const int k = rest % KV;
        const int ct = rest / KV;
        const int cout = ct * 16 + (lane & 15);
        const int cin = c * 32 + (lane >> 4) * 8 + e;
        const float v = (cin < CIN) ? J.W[jb][((size_t)k * CIN + cin) * COUT + cout] : 0.f;
        J.Wp[jb][u] = __float2bfloat16(v);
    }
}

// ---------------- sparse conv body: async-DMA staged, counted-vmcnt pipeline
// Wave owns RT*16 rows x (CTW*16) cols over all 27 taps. A staged via
// global_load_lds (whole-line mapping, XOR swizzle on the per-lane GLOBAL
// source; linear LDS dest). Masked taps -> zero page. D-deep tap pipeline,
// compile-time vmcnt counts; B ring (BR>=D) refilled at region TAIL.
// setprio(1) around the MFMA nest.
// CIN=16: native 32B rows; A-fragments for k>=16 zeroed in registers.
// FM=1 (CTG==1, COUT==32, RT==2): fuse decoder merge1 into the epilogue.
// FM=2 (CIN==64, COUT==64, CTW==2, RT==2, WPB==2): block = 32 rows x 64 cols
//   (waves split columns, same rows); fuse decoder merge2 into the epilogue:
//   m2 = relu([x, u]@Wm) + red([x, u]) with u = relu(conv) held in LDS.
template <int CIN, int COUT, int CTW, int RT, int WPB, int D, int BR, bool OUT_F32, int FM>
__device__ __forceinline__ void conv_body(
    const bf16* __restrict__ x, const bf16* __restrict__ Wp,
    const int* __restrict__ mnc, const bf16* __restrict__ zp,
    void* __restrict__ outv, int Nout, char* smem_all, int bid,
    const bf16* __restrict__ xl, const bf16* __restrict__ Wm) {
    constexpr int CINP = (CIN < 32) ? 32 : CIN;   // fragment K padding
    constexpr int NCH = CINP / 32;             // MFMA K-chunks
    constexpr int CH  = CIN / 8;               // real 16B chunks per row
    constexpr int RPI = 64 / CH;               // rows staged per instr
    constexpr int NI  = (RT * CIN) / 32;       // stage instrs per tap
    constexpr int NB  = CTW * NCH;             // B loads per tap
    constexpr int ROWS = RT * 16;
    constexpr int SLOT = ROWS * CIN * 2;       // bytes per tap tile
    constexpr int NS = D + 1;
    constexpr int TPL = (64 / ROWS) > 0 ? (64 / ROWS) : 1;  // taps per packed mnc load
    constexpr int NL = (KVOL + TPL - 1) / TPL;
    constexpr int CTG = (COUT / 16) / CTW;
    constexpr int NT = KVOL;
    static_assert(FM != 1 || (CTG == 1 && COUT == 32 && RT == 2), "FM1 shape");
    static_assert(FM != 2 || (CIN == 64 && COUT == 64 && CTW == 2 && RT == 2 && WPB == 2), "FM2 shape");

    const int w = threadIdx.x >> 6;
    if (w >= WPB) return;                      // dual-dispatch: excess waves exit
    const int lane = threadIdx.x & 63;
    const int rg = (FM == 2) ? bid : bid / CTG;
    const int cg = (FM == 2) ? w : (bid - rg * CTG);
    const int rowbase = (FM == 2) ? (rg * ROWS) : (rg * (WPB * ROWS) + w * ROWS);
    if (rowbase >= Nout) return;               // FM2: uniform across block
    const int r = lane & 15;
    const int g = lane >> 4;
    char* const sb = smem_all + w * (NS * SLOT);

    // packed mnc: load p covers taps p*TPL..p*TPL+TPL-1; lane = tp*ROWS + row
    int mnw[NL];
    {
        const int row = rowbase + (lane % ROWS);
        const int rc = (row < Nout) ? row : (Nout - 1);
#pragma unroll
        for (int p = 0; p < NL; ++p) {
            const int k = p * TPL + (lane / ROWS);
            int v = -1;
            if (k < NT) {
                const int vv = mnc[(size_t)k * Nout + rc];
                v = (row < Nout) ? vv : -1;
            }
            mnw[p] = v;
        }
    }

    short8 bring[BR][CTW][NCH];
    auto loadB = [&](int t) {
#pragma unroll
        for (int cw = 0; cw < CTW; ++cw) {
            const int ct = cg * CTW + cw;
#pragma unroll
            for (int c = 0; c < NCH; ++c)
                bring[t % BR][cw][c] = *reinterpret_cast<const short8*>(
                    Wp + (((size_t)ct * KVOL + t) * NCH + c) * 512 + lane * 8);
        }
    };

    auto stageA = [&](int t) {
        char* const dst = sb + (t % NS) * SLOT;
        const int mw = mnw[t / TPL];
        const int tb = (t % TPL) * ROWS;
        const int rl0 = lane / CH;             // row within stage instr
        const int ch0 = lane % CH;             // chunk within row
#pragma unroll
        for (int q = 0; q < NI; ++q) {
            const int rl = q * RPI + rl0;      // row within tile
            const int j = __builtin_amdgcn_ds_bpermute((tb + rl) * 4, mw);
            const int ch = (ch0 ^ (rl & (CH - 1))) * 8;        // XOR swizzle
            const bf16* src = (j >= 0) ? (x + (size_t)j * CIN) : zp;
            async16(src + ch, dst + q * 1024);
        }
    };

    f32x4 acc[RT][CTW];
#pragma unroll
    for (int rt = 0; rt < RT; ++rt)
#pragma unroll
        for (int cw = 0; cw < CTW; ++cw) {
            f32x4 z = {0.f, 0.f, 0.f, 0.f};
            acc[rt][cw] = z;
        }

    // prologue: BR B tiles first (older than all SA), then D A tiles
#pragma unroll
    for (int t = 0; t < BR; ++t) loadB(t);
#pragma unroll
    for (int t = 0; t < D; ++t) stageA(t);

    static_for<NT>([&](auto tc) {
        constexpr int t = decltype(tc)::value;
        // all prior ds_reads retired before their slot is re-DMA'd
        asm volatile("s_waitcnt lgkmcnt(0)" ::: "memory");
        if constexpr (t + D < NT) stageA(t + D);
        constexpr int WN = waitA<NT, D, BR, NI, NB>(t);
        asm volatile("s_waitcnt vmcnt(%0)" :: "n"(WN) : "memory");
        const char* sp = sb + (t % NS) * SLOT;
        short8 af[RT][NCH];
#pragma unroll
        for (int rt = 0; rt < RT; ++rt)
#pragma unroll
            for (int c = 0; c < NCH; ++c) {
                const int R = rt * 16 + r;
                const int cc = c * 4 + g;
                short8 v = {0, 0, 0, 0, 0, 0, 0, 0};
                if (cc < CH) {                 // compile-time true for CIN>=32
                    const int off = R * (CIN * 2) + ((cc ^ (R & (CH - 1))) * 16);
                    v = *reinterpret_cast<const short8*>(sp + off);
                }
                af[rt][c] = v;
            }
        __builtin_amdgcn_s_setprio(1);
#pragma unroll
        for (int c = 0; c < NCH; ++c)
#pragma unroll
            for (int cw = 0; cw < CTW; ++cw)
#pragma unroll
                for (int rt = 0; rt < RT; ++rt)
                    acc[rt][cw] = __builtin_amdgcn_mfma_f32_16x16x32_bf16(
                        af[rt][c], bring[t % BR][cw][c], acc[rt][cw], 0, 0, 0);
        __builtin_amdgcn_s_setprio(0);
        // ring refill AFTER last read of this slot (WAR, not RAW)
        if constexpr (t + BR < NT) loadB(t + BR);
    });

    if constexpr (FM == 0) {
        // epilogue: wave owns its tile outright
#pragma unroll
        for (int rt = 0; rt < RT; ++rt)
#pragma unroll
            for (int cw = 0; cw < CTW; ++cw) {
                const int col = (cg * CTW + cw) * 16 + r;
#pragma unroll
                for (int i = 0; i < 4; ++i) {
                    const int rowo = rowbase + rt * 16 + g * 4 + i;
                    if (rowo < Nout) {
                        const float v = fmaxf(acc[rt][cw][i], 0.f);
                        if (OUT_F32) ((float*)outv)[(size_t)rowo * COUT + col] = v;
                        else ((bf16*)outv)[(size_t)rowo * COUT + col] = __float2bfloat16(v);
                    }
                }
            }
    } else if constexpr (FM == 1) {
        // ---- fused merge1 epilogue (merge1 into up2) ----
        asm volatile("s_waitcnt vmcnt(0) lgkmcnt(0)" ::: "memory");
        constexpr int TS = 40;     // padded stride: 16B-aligned, bank-spread
        bf16* sbT = (bf16*)sb;
#pragma unroll
        for (int rt = 0; rt < RT; ++rt)
#pragma unroll
            for (int cw = 0; cw < CTW; ++cw) {
                const int col = cw * 16 + r;
#pragma unroll
                for (int i = 0; i < 4; ++i) {
                    const int rowl = rt * 16 + g * 4 + i;
                    sbT[rowl * TS + col] = __float2bfloat16(fmaxf(acc[rt][cw][i], 0.f));
                }
            }
        short8 bm[2][2];
#pragma unroll
        for (int cw = 0; cw < 2; ++cw)
#pragma unroll
            for (int c = 0; c < 2; ++c)
                bm[cw][c] = *reinterpret_cast<const short8*>(Wm + ((size_t)(cw * 2 + c)) * 512 + lane * 8);
#pragma unroll
        for (int p = 0; p < 2; ++p) {
            const int arow = rowbase + p * 16 + r;
            const int arc = (arow < Nout) ? arow : (Nout - 1);
            short8 a0, a1;
            a0 = *reinterpret_cast<const short8*>(sbT + (p * 16 + r) * TS + g * 8);
            a1 = *reinterpret_cast<const short8*>(xl + (size_t)arc * 32 + g * 8);
            f32x4 am[2];
#pragma unroll
            for (int cw = 0; cw < 2; ++cw) {
                f32x4 z = {0.f, 0.f, 0.f, 0.f};
                am[cw] = __builtin_amdgcn_mfma_f32_16x16x32_bf16(a0, bm[cw][0], z, 0, 0, 0);
                am[cw] = __builtin_amdgcn_mfma_f32_16x16x32_bf16(a1, bm[cw][1], am[cw], 0, 0, 0);
            }
#pragma unroll
            for (int cw = 0; cw < 2; ++cw) {
                const int j = cw * 16 + r;
#pragma unroll
                for (int i = 0; i < 4; ++i) {
                    const int rowl = p * 16 + g * 4 + i;
                    const int row = rowbase + rowl;
                    if (row < Nout) {
                        const float m = fmaxf(am[cw][i], 0.f);
                        float red;
                        if (cw == 0) {
                            red = __bfloat162float(sbT[rowl * TS + 2 * j]) +
                                  __bfloat162float(sbT[rowl * TS + 2 * j + 1]);
                        } else {
                            const bf16* s = xl + (size_t)row * 32 + 2 * (j - 16);
                            red = __bfloat162float(s[0]) + __bfloat162float(s[1]);
                        }
                        ((bf16*)outv)[(size_t)row * 32 + j] = __float2bfloat16(m + red);
                    }
                }
            }
        }
    } else {
        // ---- FM==2: fused merge2 epilogue (merge2 into lat2) ----
        // u = relu(conv), 32 rows x 64 cols (this wave holds cols cg*32..+32).
        // m2[row][j] = relu([x_row, u_row]@Wm)[j] + cat[2j] + cat[2j+1]
        asm volatile("s_waitcnt vmcnt(0) lgkmcnt(0)" ::: "memory");
        __syncthreads();           // all waves' slot reads done; slot area free
        constexpr int TS2 = 72;    // 32 x 72 bf16 = 4.5KB block-shared, 16B-aligned rows
        bf16* sbT = (bf16*)smem_all;
#pragma unroll
        for (int rt = 0; rt < RT; ++rt)
#pragma unroll
            for (int cw = 0; cw < CTW; ++cw) {
                const int col = cg * 32 + cw * 16 + r;
#pragma unroll
                for (int i = 0; i < 4; ++i) {
                    const int rowl = rt * 16 + g * 4 + i;
                    sbT[rowl * TS2 + col] = __float2bfloat16(fmaxf(acc[rt][cw][i], 0.f));
                }
            }
        __syncthreads();
        // merge: wave computes col-tiles ct = cg*2 + cw2; NCH_m = 4 (128 ch)
        short8 bm[2][4];
#pragma unroll
        for (int cw2 = 0; cw2 < 2; ++cw2)
#pragma unroll
            for (int c = 0; c < 4; ++c)
                bm[cw2][c] = *reinterpret_cast<const short8*>(
                    Wm + ((size_t)((cg * 2 + cw2) * 4 + c)) * 512 + lane * 8);
#pragma unroll
        for (int p = 0; p < 2; ++p) {
            const int arow = rowbase + p * 16 + r;
            const int arc = (arow < Nout) ? arow : (Nout - 1);
            short8 a[4];
            a[0] = *reinterpret_cast<const short8*>(x + (size_t)arc * 64 + g * 8);
            a[1] = *reinterpret_cast<const short8*>(x + (size_t)arc * 64 + 32 + g * 8);
            a[2] = *reinterpret_cast<const short8*>(sbT + (p * 16 + r) * TS2 + g * 8);
            a[3] = *reinterpret_cast<const short8*>(sbT + (p * 16 + r) * TS2 + 32 + g * 8);
            f32x4 am[2];
#pragma unroll
            for (int cw2 = 0; cw2 < 2; ++cw2) {
                f32x4 z = {0.f, 0.f, 0.f, 0.f};
                am[cw2] = z;
#pragma unroll
                for (int c = 0; c < 4; ++c)
                    am[cw2] = __builtin_amdgcn_mfma_f32_16x16x32_bf16(
                        a[c], bm[cw2][c], am[cw2], 0, 0, 0);
            }
#pragma unroll
            for (int cw2 = 0; cw2 < 2; ++cw2) {
                const int j = (cg * 2 + cw2) * 16 + r;
#pragma unroll
                for (int i = 0; i < 4; ++i) {
                    const int rowl = p * 16 + g * 4 + i;
                    const int row = rowbase + rowl;
                    if (row < Nout) {
                        const float m = fmaxf(am[cw2][i], 0.f);
                        float red;
                        if (2 * j < 64) {      // cat[2j] from x (= e2)
                            const bf16* s = x + (size_t)row * 64 + 2 * j;
                            red = __bfloat162float(s[0]) + __bfloat162float(s[1]);
                        } else {               // cat[2j] from u (LDS)
                            red = __bfloat162float(sbT[rowl * TS2 + 2 * j - 64]) +
                                  __bfloat162float(sbT[rowl * TS2 + 2 * j - 63]);
                        }
                        ((bf16*)outv)[(size_t)row * 64 + j] = __float2bfloat16(m + red);
                    }
                }
            }
        }
    }
}

template <int CIN, int COUT, int CTW, int RT, int WPB, int D, int BR, int MINW, bool OUT_F32, int FM>
__global__ __launch_bounds__(WPB * 64, MINW) void conv_async_kernel(
    const bf16* __restrict__ x, const bf16* __restrict__ Wp,
    const int* __restrict__ mnc, const bf16* __restrict__ zp,
    void* __restrict__ outv, int Nout,
    const bf16* __restrict__ xl, const bf16* __restrict__ Wm) {
    constexpr int LDSB = WPB * (D + 1) * RT * 16 * CIN * 2;
    __shared__ __align__(16) char smem[LDSB];
    conv_body<CIN, COUT, CTW, RT, WPB, D, BR, OUT_F32, FM>(x, Wp, mnc, zp, outv, Nout, smem, blockIdx.x, xl, Wm);
}

// dual dispatch: blocks [0,split) run conv A, [split,...) run conv B.
template <int CIN1, int COUT1, int CTW1, int RT1, int WPB1, int D1, int BR1, bool OF1,
          int CIN2, int COUT2, int CTW2, int RT2, int WPB2, int D2, int BR2, bool OF2, int MINW>
__global__ __launch_bounds__(256, MINW) void conv_dual_kernel(
    const bf16* __restrict__ x1, const bf16* __restrict__ Wp1, const int* __restrict__ mnc1,
    void* __restrict__ out1, int Nout1,
    const bf16* __restrict__ x2, const bf16* __restrict__ Wp2, const int* __restrict__ mnc2,
    void* __restrict__ out2, int Nout2,
    const bf16* __restrict__ zp, int split) {
    constexpr int L1 = WPB1 * (D1 + 1) * RT1 * 16 * CIN1 * 2;
    constexpr int L2 = WPB2 * (D2 + 1) * RT2 * 16 * CIN2 * 2;
    constexpr int LM = (L1 > L2) ? L1 : L2;
    __shared__ __align__(16) char smem[LM];
    if ((int)blockIdx.x < split)
        conv_body<CIN1, COUT1, CTW1, RT1, WPB1, D1, BR1, OF1, 0>(x1, Wp1, mnc1, zp, out1, Nout1, smem, blockIdx.x, nullptr, nullptr);
    else
        conv_body<CIN2, COUT2, CTW2, RT2, WPB2, D2, BR2, OF2, 0>(x2, Wp2, mnc2, zp, out2, Nout2, smem, blockIdx.x - split, nullptr, nullptr);
}

// ---------------- host ----------------
template <int CIN, int COUT, int CTW, int RT, int WPB, int D, int BR, int MINW, bool OF32>
static void launch_conv(const bf16* x, const bf16* Wp, const int* mnc, const bf16* zp,
                        void* out, int Nout, hipStream_t s) {
    constexpr int CTG = (COUT / 16) / CTW;
    constexpr int BROWS = WPB * RT * 16;
    const int RG = (Nout + BROWS - 1) / BROWS;
    conv_async_kernel<CIN, COUT, CTW, RT, WPB, D, BR, MINW, OF32, 0>
        <<<RG * CTG, WPB * 64, 0, s>>>(x, Wp, mnc, zp, out, Nout, nullptr, nullptr);
}

static size_t align_up(size_t v) { return (v + 255) & ~(size_t)255; }

extern "C" void kernel_launch(void* const* d_in, const int* in_sizes, int n_in,
                              void* d_out, int out_size, void* d_ws, size_t ws_size,
                              hipStream_t stream) {
    const float* feat     = (const float*)d_in[0];
    const int*   nbr0     = (const int*)d_in[1];
    const int*   mask0    = (const int*)d_in[2];
    const int*   nbr1     = (const int*)d_in[3];
    const int*   mask1    = (const int*)d_in[4];
    const int*   nbr_down = (const int*)d_in[5];
    const int*   mask_down= (const int*)d_in[6];
    const int*   nbr_up   = (const int*)d_in[7];
    const int*   mask_up  = (const int*)d_in[8];
    const float* W_in     = (const float*)d_in[9];
    const float* W_enc1   = (const float*)d_in[10];
    const float* W_down   = (const float*)d_in[11];
    const float* W_enc2   = (const float*)d_in[12];
    const float* W_lat2   = (const float*)d_in[13];
    const float* W_merge2 = (const float*)d_in[14];
    const float* W_up2    = (const float*)d_in[15];
    const float* W_lat1   = (const float*)d_in[16];
    const float* W_merge1 = (const float*)d_in[17];
    const float* W_up1    = (const float*)d_in[18];

    const int N0 = in_sizes[0] / 16;
    const int N1 = in_sizes[3] / KVOL;

    char* p = (char*)d_ws;
    auto carve = [&](size_t bytes) { char* q = p; p += align_up(bytes); return q; };

    bf16* featb = (bf16*)carve((size_t)N0 * 16 * 2);   // native 16 ch
    bf16* x0    = (bf16*)carve((size_t)N0 * 32 * 2);
    bf16* e1    = (bf16*)carve((size_t)N0 * 32 * 2);
    bf16* xd    = (bf16*)carve((size_t)N1 * 64 * 2);
    bf16* e2    = (bf16*)carve((size_t)N1 * 64 * 2);
    bf16* m2    = (bf16*)carve((size_t)N1 * 64 * 2);
    bf16* xl1   = (bf16*)carve((size_t)N0 * 32 * 2);
    bf16* m1    = (bf16*)carve((size_t)N0 * 32 * 2);
    bf16* zp    = (bf16*)carve(256);                   // zero page (128B used)

    int* mnc0 = (int*)carve((size_t)KVOL * N0 * 4);
    int* mnc1 = (int*)carve((size_t)KVOL * N1 * 4);
    int* mncd = (int*)carve((size_t)KVOL * N1 * 4);
    int* mncu = (int*)carve((size_t)KVOL * N0 * 4);

    const int sz_in   = 2 * KVOL * 1 * 512;
    const int sz_enc1 = 2 * KVOL * 1 * 512;
    const int sz_down = 4 * KVOL * 1 * 512;
    const int sz_enc2 = 4 * KVOL * 2 * 512;
    const int sz_lat2 = 4 * KVOL * 2 * 512;
    const int sz_up2  = 2 * KVOL * 2 * 512;
    const int sz_lat1 = 2 * KVOL * 1 * 512;
    const int sz_up1  = 2 * KVOL * 1 * 512;
    const int sz_wm2  = 4 * 1 * 4 * 512;
    const int sz_wm1  = 2 * 1 * 2 * 512;

    bf16* Wp_in   = (bf16*)carve((size_t)sz_in * 2);
    bf16* Wp_enc1 = (bf16*)carve((size_t)sz_enc1 * 2);
    bf16* Wp_down = (bf16*)carve((size_t)sz_down * 2);
    bf16* Wp_enc2 = (bf16*)carve((size_t)sz_enc2 * 2);
    bf16* Wp_lat2 = (bf16*)carve((size_t)sz_lat2 * 2);
    bf16* Wp_up2  = (bf16*)carve((size_t)sz_up2 * 2);
    bf16* Wp_lat1 = (bf16*)carve((size_t)sz_lat1 * 2);
    bf16* Wp_up1  = (bf16*)carve((size_t)sz_up1 * 2);
    bf16* Wmp2    = (bf16*)carve((size_t)sz_wm2 * 2);
    bf16* Wmp1    = (bf16*)carve((size_t)sz_wm1 * 2);

    // --- fused prep (cvt + mnc x4 + pack + zero page), one dispatch ---
    {
        PrepArgs P;
        P.feat = feat; P.featb = featb; P.n_cvt = N0 * 4;
        const int* nbs[4] = {nbr0, nbr1, nbr_down, nbr_up};
        const int* mks[4] = {mask0, mask1, mask_down, mask_up};
        int* mns[4] = {mnc0, mnc1, mncd, mncu};
        const int szs4[4] = {KVOL * N0 / 4, KVOL * N1 / 4, KVOL * N1 / 4, KVOL * N0 / 4};
        int macc = 0;
        for (int i = 0; i < 4; ++i) {
            P.nbr[i] = nbs[i]; P.mask[i] = mks[i]; P.mnc[i] = mns[i];
            P.mnc_start[i] = macc; macc += szs4[i];
        }
        P.mnc_start[4] = macc;

        const float* Ws[10] = {W_in, W_enc1, W_down, W_enc2, W_lat2, W_up2, W_lat1, W_up1, W_merge2, W_merge1};
        bf16* Wps[10] = {Wp_in, Wp_enc1, Wp_down, Wp_enc2, Wp_lat2, Wp_up2, Wp_lat1, Wp_up1, Wmp2, Wmp1};
        const int cins[10]  = {16, 32, 32, 64, 64, 64, 32, 32, 128, 64};
        const int couts[10] = {32, 32, 64, 64, 64, 32, 32, 32, 64, 32};
        const int kvs[10]   = {KVOL, KVOL, KVOL, KVOL, KVOL, KVOL, KVOL, KVOL, 1, 1};
        const int szs[10]   = {sz_in, sz_enc1, sz_down, sz_enc2, sz_lat2, sz_up2, sz_lat1, sz_up1, sz_wm2, sz_wm1};
        int acc = 0;
        for (int i = 0; i < 10; ++i) {
            P.pj.W[i] = Ws[i]; P.pj.Wp[i] = Wps[i];
            P.pj.cin[i] = cins[i]; P.pj.cout[i] = couts[i]; P.pj.kvol[i] = kvs[i];
            P.pj.start[i] = acc; acc += szs[i];
        }
        P.pj.start[10] = acc;
        P.n_pack = acc;
        P.zp = (int*)zp;

        const int total = P.n_cvt + macc + acc;
        prep_all_kernel<<<(total + 255) / 256, 256, 0, stream>>>(P);
    }

    // --- network ---
    // conv_input: native CIN=16.  CIN32-N0 convs: WPB=2/RT=4/D=3/BR=4.
    // dual(down+lat1).  enc2: WPB=2/RT=2.
    // lat2+merge2 (FM=2): block = 32 rows x 64 cols; m2 written directly,
    //   xl2 never materialized; merge2 dispatch eliminated.
    // up2+merge1 (FM=1): D=2.
    launch_conv<16, 32, 2, 4, 2, 3, 4, 2, false>(featb, Wp_in, mnc0, zp, x0, N0, stream);
    launch_conv<32, 32, 2, 4, 2, 3, 4, 2, false>(x0, Wp_enc1, mnc0, zp, e1, N0, stream);

    {
        // down: CIN32/COUT64/CTW2/RT1/WPB4/D3/BR4 -> CTG=2, BROWS=64
        const int g_down = ((N1 + 63) / 64) * 2;
        // lat1: CIN32/COUT32/CTW2/RT4/WPB2/D3/BR4 -> CTG=1, BROWS=128
        const int g_lat1 = (N0 + 127) / 128;
        conv_dual_kernel<32, 64, 2, 1, 4, 3, 4, false,
                         32, 32, 2, 4, 2, 3, 4, false, 2>
            <<<g_down + g_lat1, 256, 0, stream>>>(
                e1, Wp_down, mncd, xd, N1,
                e1, Wp_lat1, mnc0, xl1, N0,
                zp, g_down);
    }

    launch_conv<64, 64, 2, 2, 2, 3, 4, 1, false>(xd, Wp_enc2, mnc1, zp, e2, N1, stream);

    {
        // lat2 + fused merge2: block covers 32 rows x all 64 cols
        const int RG = (N1 + 31) / 32;
        conv_async_kernel<64, 64, 2, 2, 2, 3, 4, 1, false, 2>
            <<<RG, 128, 0, stream>>>(e2, Wp_lat2, mnc1, zp, m2, N1, nullptr, Wmp2);
    }

    {
        // up2 + fused merge1: writes m1 directly (u2 never hits global)
        constexpr int BROWS = 2 * 2 * 16;   // WPB*RT*16 = 64
        const int RG = (N0 + BROWS - 1) / BROWS;
        conv_async_kernel<64, 32, 2, 2, 2, 2, 4, 2, false, 1>
            <<<RG, 128, 0, stream>>>(m2, Wp_up2, mncu, zp, m1, N0, xl1, Wmp1);
    }

    launch_conv<32, 32, 2, 4, 2, 3, 4, 2, true>(m1, Wp_up1, mnc0, zp, (float*)d_out, N0, stream);
}

// Round 18
// 173.202 us; speedup vs baseline: 9.5381x; 1.0133x over previous
//
#include <hip/hip_runtime.h>
#include <hip/hip_bf16.h>
#include <utility>

#define KVOL 27

using bf16 = __hip_bfloat16;
typedef __attribute__((ext_vector_type(8))) short short8;
typedef __attribute__((ext_vector_type(4))) short short4v;
typedef __attribute__((ext_vector_type(4))) float f32x4;
typedef __attribute__((ext_vector_type(4))) int int4v;

// async global->LDS 16B DMA; lds base is wave-uniform, HW writes lane i at base+i*16
__device__ __forceinline__ void async16(const void* g, void* l) {
    __builtin_amdgcn_global_load_lds(
        (const __attribute__((address_space(1))) void*)g,
        (__attribute__((address_space(3))) void*)l, 16, 0, 0);
}

template <class F, int... Is>
__device__ __forceinline__ void static_for_impl(F&& f, std::integer_sequence<int, Is...>) {
    (f(std::integral_constant<int, Is>{}), ...);
}
template <int N, class F>
__device__ __forceinline__ void static_for(F&& f) {
    static_for_impl(static_cast<F&&>(f), std::make_integer_sequence<int, N>{});
}

// vmcnt immediate guaranteeing stageA(t) complete (R3-proven form; the
// prologue branch is the order-robust lower bound on ops younger than SA(t)).
template <int NT, int D, int BR, int NI, int NB>
constexpr int waitA(int t) {
    int s = ((t + D < NT) ? NI : 0);            // SA(t+D), issued before the wait
    if (t < D) {
        for (int j = 0; j < t; ++j)
            s += ((j + D < NT) ? NI : 0) + ((j + BR < NT) ? NB : 0);
    } else {
        s += ((t - D + BR < NT) ? NB : 0);      // loadB tail of SA(t)'s region
        for (int j = t - D + 1; j < t; ++j)
            s += ((j + D < NT) ? NI : 0) + ((j + BR < NT) ? NB : 0);
    }
    return s;
}

// ---------------- prep machinery (generic: empty slots allowed) ----------
struct PackJobs {
    const float* W[10];
    bf16* Wp[10];
    int cin[10];
    int cout[10];
    int kvol[10];
    int start[11];
};

struct PrepArgs {
    const float* feat; bf16* featb; int n_cvt;          // 0 if no cvt job
    const int* nbr[4]; const int* mask[4]; int* mnc[4];
    int mnc_start[5];                                   // prefix, units of 4 ints
    PackJobs pj; int n_pack;
    int* zp;
};

__device__ __forceinline__ void prep_mnc_pack_body(const PrepArgs& P, int T) {
    // --- mnc compress (4 ints/thread) ---
    if (T < P.mnc_start[4]) {
        int tb = 3;
#pragma unroll
        for (int q = 2; q >= 0; --q) if (T < P.mnc_start[q + 1]) tb = q;
        const int off = (T - P.mnc_start[tb]) * 4;
        const int4v nb = *reinterpret_cast<const int4v*>(P.nbr[tb] + off);
        const int4v mk = *reinterpret_cast<const int4v*>(P.mask[tb] + off);
        int4v r;
        r.x = mk.x ? nb.x : -1;
        r.y = mk.y ? nb.y : -1;
        r.z = mk.z ? nb.z : -1;
        r.w = mk.w ? nb.w : -1;
        *reinterpret_cast<int4v*>(P.mnc[tb] + off) = r;
        return;
    }
    T -= P.mnc_start[4];

    // --- weight pack ---
    if (T < P.n_pack) {
        const PackJobs& J = P.pj;
        int jb = 9;
#pragma unroll
        for (int q = 8; q >= 0; --q) if (T < J.start[q + 1]) jb = q;
        const int u = T - J.start[jb];
        const int CIN = J.cin[jb], COUT = J.cout[jb], KV = J.kvol[jb];
        const int CINP = CIN < 32 ? 32 : CIN;
        const int NCH = CINP / 32;
        const int e = u & 7;
        const int lane = (u >> 3) & 63;
        int rest = u >> 9;
        const int c = rest % NCH; rest /= NCH;
        const int k = rest % KV;
        const int ct = rest / KV;
        const int cout = ct * 16 + (lane & 15);
        const int cin = c * 32 + (lane >> 4) * 8 + e;
        const float v = (cin < CIN) ? J.W[jb][((size_t)k * CIN + cin) * COUT + cout] : 0.f;
        J.Wp[jb][u] = __float2bfloat16(v);
    }
}

__global__ __launch_bounds__(256) void prep_all_kernel(PrepArgs P) {
    if (blockIdx.x == 0 && threadIdx.x < 8) {
        int4v z = {0, 0, 0, 0};
        reinterpret_cast<int4v*>(P.zp)[threadIdx.x] = z;  // 128B zero page
    }
    int T = blockIdx.x * 256 + threadIdx.x;

    // --- fp32 -> bf16 convert, native 16ch (4 elems/thread) ---
    if (T < P.n_cvt) {
        const int row = T >> 2;
        const int c4 = (T & 3) * 4;
        const float4 v = *reinterpret_cast<const float4*>(P.feat + (size_t)row * 16 + c4);
        short4v o;
        bf16 b0 = __float2bfloat16(v.x); o.x = *reinterpret_cast<short*>(&b0);
        bf16 b1 = __float2bfloat16(v.y); o.y = *reinterpret_cast<short*>(&b1);
        bf16 b2 = __float2bfloat16(v.z); o.z = *reinterpret_cast<short*>(&b2);
        bf16 b3 = __float2bfloat16(v.w); o.w = *reinterpret_cast<short*>(&b3);
        *reinterpret_cast<short4v*>(P.featb + (size_t)row * 16 + c4) = o;
        return;
    }
    T -= P.n_cvt;
    prep_mnc_pack_body(P, T);
}

// ---------------- sparse conv body: async-DMA staged, counted-vmcnt pipeline
// Wave owns RT*16 rows x (CTW*16) cols over all 27 taps. A staged via
// global_load_lds (whole-line mapping, XOR swizzle on the per-lane GLOBAL
// source; linear LDS dest). Masked taps -> zero page. D-deep tap pipeline,
// compile-time vmcnt counts; B ring (BR>=D) refilled at region TAIL.
// setprio(1) around the MFMA nest.
// CIN=16: native 32B rows; A-fragments for k>=16 zeroed in registers.
// FM=1 (CTG==1, COUT==32, RT==2): fuse decoder merge1 into the epilogue.
// FM=2 (CIN==64, COUT==64, CTW==2, RT==2, WPB==2): block = 32 rows x 64 cols
//   (waves split columns, same rows); fuse decoder merge2 into the epilogue.
template <int CIN, int COUT, int CTW, int RT, int WPB, int D, int BR, bool OUT_F32, int FM>
__device__ __forceinline__ void conv_body(
    const bf16* __restrict__ x, const bf16* __restrict__ Wp,
    const int* __restrict__ mnc, const bf16* __restrict__ zp,
    void* __restrict__ outv, int Nout, char* smem_all, int bid,
    const bf16* __restrict__ xl, const bf16* __restrict__ Wm) {
    constexpr int CINP = (CIN < 32) ? 32 : CIN;   // fragment K padding
    constexpr int NCH = CINP / 32;             // MFMA K-chunks
    constexpr int CH  = CIN / 8;               // real 16B chunks per row
    constexpr int RPI = 64 / CH;               // rows staged per instr
    constexpr int NI  = (RT * CIN) / 32;       // stage instrs per tap
    constexpr int NB  = CTW * NCH;             // B loads per tap
    constexpr int ROWS = RT * 16;
    constexpr int SLOT = ROWS * CIN * 2;       // bytes per tap tile
    constexpr int NS = D + 1;
    constexpr int TPL = (64 / ROWS) > 0 ? (64 / ROWS) : 1;  // taps per packed mnc load
    constexpr int NL = (KVOL + TPL - 1) / TPL;
    constexpr int CTG = (COUT / 16) / CTW;
    constexpr int NT = KVOL;
    static_assert(FM != 1 || (CTG == 1 && COUT == 32 && RT == 2), "FM1 shape");
    static_assert(FM != 2 || (CIN == 64 && COUT == 64 && CTW == 2 && RT == 2 && WPB == 2), "FM2 shape");

    const int w = threadIdx.x >> 6;
    if (w >= WPB) return;                      // dual-dispatch: excess waves exit
    const int lane = threadIdx.x & 63;
    const int rg = (FM == 2) ? bid : bid / CTG;
    const int cg = (FM == 2) ? w : (bid - rg * CTG);
    const int rowbase = (FM == 2) ? (rg * ROWS) : (rg * (WPB * ROWS) + w * ROWS);
    if (rowbase >= Nout) return;               // FM2: uniform across block
    const int r = lane & 15;
    const int g = lane >> 4;
    char* const sb = smem_all + w * (NS * SLOT);

    // packed mnc: load p covers taps p*TPL..p*TPL+TPL-1; lane = tp*ROWS + row
    int mnw[NL];
    {
        const int row = rowbase + (lane % ROWS);
        const int rc = (row < Nout) ? row : (Nout - 1);
#pragma unroll
        for (int p = 0; p < NL; ++p) {
            const int k = p * TPL + (lane / ROWS);
            int v = -1;
            if (k < NT) {
                const int vv = mnc[(size_t)k * Nout + rc];
                v = (row < Nout) ? vv : -1;
            }
            mnw[p] = v;
        }
    }

    short8 bring[BR][CTW][NCH];
    auto loadB = [&](int t) {
#pragma unroll
        for (int cw = 0; cw < CTW; ++cw) {
            const int ct = cg * CTW + cw;
#pragma unroll
            for (int c = 0; c < NCH; ++c)
                bring[t % BR][cw][c] = *reinterpret_cast<const short8*>(
                    Wp + (((size_t)ct * KVOL + t) * NCH + c) * 512 + lane * 8);
        }
    };

    auto stageA = [&](int t) {
        char* const dst = sb + (t % NS) * SLOT;
        const int mw = mnw[t / TPL];
        const int tb = (t % TPL) * ROWS;
        const int rl0 = lane / CH;             // row within stage instr
        const int ch0 = lane % CH;             // chunk within row
#pragma unroll
        for (int q = 0; q < NI; ++q) {
            const int rl = q * RPI + rl0;      // row within tile
            const int j = __builtin_amdgcn_ds_bpermute((tb + rl) * 4, mw);
            const int ch = (ch0 ^ (rl & (CH - 1))) * 8;        // XOR swizzle
            const bf16* src = (j >= 0) ? (x + (size_t)j * CIN) : zp;
            async16(src + ch, dst + q * 1024);
        }
    };

    f32x4 acc[RT][CTW];
#pragma unroll
    for (int rt = 0; rt < RT; ++rt)
#pragma unroll
        for (int cw = 0; cw < CTW; ++cw) {
            f32x4 z = {0.f, 0.f, 0.f, 0.f};
            acc[rt][cw] = z;
        }

    // prologue: BR B tiles first (older than all SA), then D A tiles
#pragma unroll
    for (int t = 0; t < BR; ++t) loadB(t);
#pragma unroll
    for (int t = 0; t < D; ++t) stageA(t);

    static_for<NT>([&](auto tc) {
        constexpr int t = decltype(tc)::value;
        // all prior ds_reads retired before their slot is re-DMA'd
        asm volatile("s_waitcnt lgkmcnt(0)" ::: "memory");
        if constexpr (t + D < NT) stageA(t + D);
        constexpr int WN = waitA<NT, D, BR, NI, NB>(t);
        asm volatile("s_waitcnt vmcnt(%0)" :: "n"(WN) : "memory");
        const char* sp = sb + (t % NS) * SLOT;
        short8 af[RT][NCH];
#pragma unroll
        for (int rt = 0; rt < RT; ++rt)
#pragma unroll
            for (int c = 0; c < NCH; ++c) {
                const int R = rt * 16 + r;
                const int cc = c * 4 + g;
                short8 v = {0, 0, 0, 0, 0, 0, 0, 0};
                if (cc < CH) {                 // compile-time true for CIN>=32
                    const int off = R * (CIN * 2) + ((cc ^ (R & (CH - 1))) * 16);
                    v = *reinterpret_cast<const short8*>(sp + off);
                }
                af[rt][c] = v;
            }
        __builtin_amdgcn_s_setprio(1);
#pragma unroll
        for (int c = 0; c < NCH; ++c)
#pragma unroll
            for (int cw = 0; cw < CTW; ++cw)
#pragma unroll
                for (int rt = 0; rt < RT; ++rt)
                    acc[rt][cw] = __builtin_amdgcn_mfma_f32_16x16x32_bf16(
                        af[rt][c], bring[t % BR][cw][c], acc[rt][cw], 0, 0, 0);
        __builtin_amdgcn_s_setprio(0);
        // ring refill AFTER last read of this slot (WAR, not RAW)
        if constexpr (t + BR < NT) loadB(t + BR);
    });

    if constexpr (FM == 0) {
        // epilogue: wave owns its tile outright
#pragma unroll
        for (int rt = 0; rt < RT; ++rt)
#pragma unroll
            for (int cw = 0; cw < CTW; ++cw) {
                const int col = (cg * CTW + cw) * 16 + r;
#pragma unroll
                for (int i = 0; i < 4; ++i) {
                    const int rowo = rowbase + rt * 16 + g * 4 + i;
                    if (rowo < Nout) {
                        const float v = fmaxf(acc[rt][cw][i], 0.f);
                        if (OUT_F32) ((float*)outv)[(size_t)rowo * COUT + col] = v;
                        else ((bf16*)outv)[(size_t)rowo * COUT + col] = __float2bfloat16(v);
                    }
                }
            }
    } else if constexpr (FM == 1) {
        // ---- fused merge1 epilogue (merge1 into up2) ----
        asm volatile("s_waitcnt vmcnt(0) lgkmcnt(0)" ::: "memory");
        constexpr int TS = 40;     // padded stride: 16B-aligned, bank-spread
        bf16* sbT = (bf16*)sb;
#pragma unroll
        for (int rt = 0; rt < RT; ++rt)
#pragma unroll
            for (int cw = 0; cw < CTW; ++cw) {
                const int col = cw * 16 + r;
#pragma unroll
                for (int i = 0; i < 4; ++i) {
                    const int rowl = rt * 16 + g * 4 + i;
                    sbT[rowl * TS + col] = __float2bfloat16(fmaxf(acc[rt][cw][i], 0.f));
                }
            }
        short8 bm[2][2];
#pragma unroll
        for (int cw = 0; cw < 2; ++cw)
#pragma unroll
            for (int c = 0; c < 2; ++c)
                bm[cw][c] = *reinterpret_cast<const short8*>(Wm + ((size_t)(cw * 2 + c)) * 512 + lane * 8);
#pragma unroll
        for (int p = 0; p < 2; ++p) {
            const int arow = rowbase + p * 16 + r;
            const int arc = (arow < Nout) ? arow : (Nout - 1);
            short8 a0, a1;
            a0 = *reinterpret_cast<const short8*>(sbT + (p * 16 + r) * TS + g * 8);
            a1 = *reinterpret_cast<const short8*>(xl + (size_t)arc * 32 + g * 8);
            f32x4 am[2];
#pragma unroll
            for (int cw = 0; cw < 2; ++cw) {
                f32x4 z = {0.f, 0.f, 0.f, 0.f};
                am[cw] = __builtin_amdgcn_mfma_f32_16x16x32_bf16(a0, bm[cw][0], z, 0, 0, 0);
                am[cw] = __builtin_amdgcn_mfma_f32_16x16x32_bf16(a1, bm[cw][1], am[cw], 0, 0, 0);
            }
#pragma unroll
            for (int cw = 0; cw < 2; ++cw) {
                const int j = cw * 16 + r;
#pragma unroll
                for (int i = 0; i < 4; ++i) {
                    const int rowl = p * 16 + g * 4 + i;
                    const int row = rowbase + rowl;
                    if (row < Nout) {
                        const float m = fmaxf(am[cw][i], 0.f);
                        float red;
                        if (cw == 0) {
                            red = __bfloat162float(sbT[rowl * TS + 2 * j]) +
                                  __bfloat162float(sbT[rowl * TS + 2 * j + 1]);
                        } else {
                            const bf16* s = xl + (size_t)row * 32 + 2 * (j - 16);
                            red = __bfloat162float(s[0]) + __bfloat162float(s[1]);
                        }
                        ((bf16*)outv)[(size_t)row * 32 + j] = __float2bfloat16(m + red);
                    }
                }
            }
        }
    } else {
        // ---- FM==2: fused merge2 epilogue (merge2 into lat2) ----
        asm volatile("s_waitcnt vmcnt(0) lgkmcnt(0)" ::: "memory");
        __syncthreads();           // all waves' slot reads done; slot area free
        constexpr int TS2 = 72;    // 32 x 72 bf16, 16B-aligned rows
        bf16* sbT = (bf16*)smem_all;
#pragma unroll
        for (int rt = 0; rt < RT; ++rt)
#pragma unroll
            for (int cw = 0; cw < CTW; ++cw) {
                const int col = cg * 32 + cw * 16 + r;
#pragma unroll
                for (int i = 0; i < 4; ++i) {
                    const int rowl = rt * 16 + g * 4 + i;
                    sbT[rowl * TS2 + col] = __float2bfloat16(fmaxf(acc[rt][cw][i], 0.f));
                }
            }
        __syncthreads();
        short8 bm[2][4];
#pragma unroll
        for (int cw2 = 0; cw2 < 2; ++cw2)
#pragma unroll
            for (int c = 0; c < 4; ++c)
                bm[cw2][c] = *reinterpret_cast<const short8*>(
                    Wm + ((size_t)((cg * 2 + cw2) * 4 + c)) * 512 + lane * 8);
#pragma unroll
        for (int p = 0; p < 2; ++p) {
            const int arow = rowbase + p * 16 + r;
            const int arc = (arow < Nout) ? arow : (Nout - 1);
            short8 a[4];
            a[0] = *reinterpret_cast<const short8*>(x + (size_t)arc * 64 + g * 8);
            a[1] = *reinterpret_cast<const short8*>(x + (size_t)arc * 64 + 32 + g * 8);
            a[2] = *reinterpret_cast<const short8*>(sbT + (p * 16 + r) * TS2 + g * 8);
            a[3] = *reinterpret_cast<const short8*>(sbT + (p * 16 + r) * TS2 + 32 + g * 8);
            f32x4 am[2];
#pragma unroll
            for (int cw2 = 0; cw2 < 2; ++cw2) {
                f32x4 z = {0.f, 0.f, 0.f, 0.f};
                am[cw2] = z;
#pragma unroll
                for (int c = 0; c < 4; ++c)
                    am[cw2] = __builtin_amdgcn_mfma_f32_16x16x32_bf16(
                        a[c], bm[cw2][c], am[cw2], 0, 0, 0);
            }
#pragma unroll
            for (int cw2 = 0; cw2 < 2; ++cw2) {
                const int j = (cg * 2 + cw2) * 16 + r;
#pragma unroll
                for (int i = 0; i < 4; ++i) {
                    const int rowl = p * 16 + g * 4 + i;
                    const int row = rowbase + rowl;
                    if (row < Nout) {
                        const float m = fmaxf(am[cw2][i], 0.f);
                        float red;
                        if (2 * j < 64) {      // cat[2j] from x (= e2)
                            const bf16* s = x + (size_t)row * 64 + 2 * j;
                            red = __bfloat162float(s[0]) + __bfloat162float(s[1]);
                        } else {               // cat[2j] from u (LDS)
                            red = __bfloat162float(sbT[rowl * TS2 + 2 * j - 64]) +
                                  __bfloat162float(sbT[rowl * TS2 + 2 * j - 63]);
                        }
                        ((bf16*)outv)[(size_t)row * 64 + j] = __float2bfloat16(m + red);
                    }
                }
            }
        }
    }
}

template <int CIN, int COUT, int CTW, int RT, int WPB, int D, int BR, int MINW, bool OUT_F32, int FM>
__global__ __launch_bounds__(WPB * 64, MINW) void conv_async_kernel(
    const bf16* __restrict__ x, const bf16* __restrict__ Wp,
    const int* __restrict__ mnc, const bf16* __restrict__ zp,
    void* __restrict__ outv, int Nout,
    const bf16* __restrict__ xl, const bf16* __restrict__ Wm) {
    constexpr int LDSB = WPB * (D + 1) * RT * 16 * CIN * 2;
    __shared__ __align__(16) char smem[LDSB];
    conv_body<CIN, COUT, CTW, RT, WPB, D, BR, OUT_F32, FM>(x, Wp, mnc, zp, outv, Nout, smem, blockIdx.x, xl, Wm);
}

// dual dispatch: blocks [0,split) run conv A, [split,...) run conv B.
template <int CIN1, int COUT1, int CTW1, int RT1, int WPB1, int D1, int BR1, bool OF1,
          int CIN2, int COUT2, int CTW2, int RT2, int WPB2, int D2, int BR2, bool OF2, int MINW>
__global__ __launch_bounds__(256, MINW) void conv_dual_kernel(
    const bf16* __restrict__ x1, const bf16* __restrict__ Wp1, const int* __restrict__ mnc1,
    void* __restrict__ out1, int Nout1,
    const bf16* __restrict__ x2, const bf16* __restrict__ Wp2, const int* __restrict__ mnc2,
    void* __restrict__ out2, int Nout2,
    const bf16* __restrict__ zp, int split) {
    constexpr int L1 = WPB1 * (D1 + 1) * RT1 * 16 * CIN1 * 2;
    constexpr int L2 = WPB2 * (D2 + 1) * RT2 * 16 * CIN2 * 2;
    constexpr int LM = (L1 > L2) ? L1 : L2;
    __shared__ __align__(16) char smem[LM];
    if ((int)blockIdx.x < split)
        conv_body<CIN1, COUT1, CTW1, RT1, WPB1, D1, BR1, OF1, 0>(x1, Wp1, mnc1, zp, out1, Nout1, smem, blockIdx.x, nullptr, nullptr);
    else
        conv_body<CIN2, COUT2, CTW2, RT2, WPB2, D2, BR2, OF2, 0>(x2, Wp2, mnc2, zp, out2, Nout2, smem, blockIdx.x - split, nullptr, nullptr);
}

// conv_input + prep_b co-dispatch: blocks [0,split) run conv_input,
// [split,...) run the remaining prep (mnc1/mncd/mncu + packs 1..9).
// Independent by construction: conv_input reads featb/mnc0/Wp_in (prep_a),
// prep_b writes tables/weights consumed only by later kernels.
template <int CIN, int COUT, int CTW, int RT, int WPB, int D, int BR, int MINW, bool OF32>
__global__ __launch_bounds__(256, MINW) void conv_prepb_kernel(
    const bf16* __restrict__ x, const bf16* __restrict__ Wp,
    const int* __restrict__ mnc, const bf16* __restrict__ zp,
    void* __restrict__ outv, int Nout, PrepArgs B, int split) {
    constexpr int LDSB = WPB * (D + 1) * RT * 16 * CIN * 2;
    __shared__ __align__(16) char smem[LDSB];
    if ((int)blockIdx.x < split) {
        conv_body<CIN, COUT, CTW, RT, WPB, D, BR, OF32, 0>(
            x, Wp, mnc, zp, outv, Nout, smem, blockIdx.x, nullptr, nullptr);
    } else {
        const int T = ((int)blockIdx.x - split) * 256 + threadIdx.x;
        prep_mnc_pack_body(B, T);
    }
}

// ---------------- host ----------------
template <int CIN, int COUT, int CTW, int RT, int WPB, int D, int BR, int MINW, bool OF32>
static void launch_conv(const bf16* x, const bf16* Wp, const int* mnc, const bf16* zp,
                        void* out, int Nout, hipStream_t s) {
    constexpr int CTG = (COUT / 16) / CTW;
    constexpr int BROWS = WPB * RT * 16;
    const int RG = (Nout + BROWS - 1) / BROWS;
    conv_async_kernel<CIN, COUT, CTW, RT, WPB, D, BR, MINW, OF32, 0>
        <<<RG * CTG, WPB * 64, 0, s>>>(x, Wp, mnc, zp, out, Nout, nullptr, nullptr);
}

static size_t align_up(size_t v) { return (v + 255) & ~(size_t)255; }

extern "C" void kernel_launch(void* const* d_in, const int* in_sizes, int n_in,
                              void* d_out, int out_size, void* d_ws, size_t ws_size,
                              hipStream_t stream) {
    const float* feat     = (const float*)d_in[0];
    const int*   nbr0     = (const int*)d_in[1];
    const int*   mask0    = (const int*)d_in[2];
    const int*   nbr1     = (const int*)d_in[3];
    const int*   mask1    = (const int*)d_in[4];
    const int*   nbr_down = (const int*)d_in[5];
    const int*   mask_down= (const int*)d_in[6];
    const int*   nbr_up   = (const int*)d_in[7];
    const int*   mask_up  = (const int*)d_in[8];
    const float* W_in     = (const float*)d_in[9];
    const float* W_enc1   = (const float*)d_in[10];
    const float* W_down   = (const float*)d_in[11];
    const float* W_enc2   = (const float*)d_in[12];
    const float* W_lat2   = (const float*)d_in[13];
    const float* W_merge2 = (const float*)d_in[14];
    const float* W_up2    = (const float*)d_in[15];
    const float* W_lat1   = (const float*)d_in[16];
    const float* W_merge1 = (const float*)d_in[17];
    const float* W_up1    = (const float*)d_in[18];

    const int N0 = in_sizes[0] / 16;
    const int N1 = in_sizes[3] / KVOL;

    char* p = (char*)d_ws;
    auto carve = [&](size_t bytes) { char* q = p; p += align_up(bytes); return q; };

    bf16* featb = (bf16*)carve((size_t)N0 * 16 * 2);   // native 16 ch
    bf16* x0    = (bf16*)carve((size_t)N0 * 32 * 2);
    bf16* e1    = (bf16*)carve((size_t)N0 * 32 * 2);
    bf16* xd    = (bf16*)carve((size_t)N1 * 64 * 2);
    bf16* e2    = (bf16*)carve((size_t)N1 * 64 * 2);
    bf16* m2    = (bf16*)carve((size_t)N1 * 64 * 2);
    bf16* xl1   = (bf16*)carve((size_t)N0 * 32 * 2);
    bf16* m1    = (bf16*)carve((size_t)N0 * 32 * 2);
    bf16* zp    = (bf16*)carve(256);                   // zero page (128B used)

    int* mnc0 = (int*)carve((size_t)KVOL * N0 * 4);
    int* mnc1 = (int*)carve((size_t)KVOL * N1 * 4);
    int* mncd = (int*)carve((size_t)KVOL * N1 * 4);
    int* mncu = (int*)carve((size_t)KVOL * N0 * 4);

    const int sz_in   = 2 * KVOL * 1 * 512;
    const int sz_enc1 = 2 * KVOL * 1 * 512;
    const int sz_down = 4 * KVOL * 1 * 512;
    const int sz_enc2 = 4 * KVOL * 2 * 512;
    const int sz_lat2 = 4 * KVOL * 2 * 512;
    const int sz_up2  = 2 * KVOL * 2 * 512;
    const int sz_lat1 = 2 * KVOL * 1 * 512;
    const int sz_up1  = 2 * KVOL * 1 * 512;
    const int sz_wm2  = 4 * 1 * 4 * 512;
    const int sz_wm1  = 2 * 1 * 2 * 512;

    bf16* Wp_in   = (bf16*)carve((size_t)sz_in * 2);
    bf16* Wp_enc1 = (bf16*)carve((size_t)sz_enc1 * 2);
    bf16* Wp_down = (bf16*)carve((size_t)sz_down * 2);
    bf16* Wp_enc2 = (bf16*)carve((size_t)sz_enc2 * 2);
    bf16* Wp_lat2 = (bf16*)carve((size_t)sz_lat2 * 2);
    bf16* Wp_up2  = (bf16*)carve((size_t)sz_up2 * 2);
    bf16* Wp_lat1 = (bf16*)carve((size_t)sz_lat1 * 2);
    bf16* Wp_up1  = (bf16*)carve((size_t)sz_up1 * 2);
    bf16* Wmp2    = (bf16*)carve((size_t)sz_wm2 * 2);
    bf16* Wmp1    = (bf16*)carve((size_t)sz_wm1 * 2);

    // --- prep_a: cvt + mnc0 + W_in pack + zero page ---
    {
        PrepArgs P;
        P.feat = feat; P.featb = featb; P.n_cvt = N0 * 4;
        const int m0q = KVOL * N0 / 4;
        for (int i = 0; i < 4; ++i) { P.nbr[i] = nbr0; P.mask[i] = mask0; P.mnc[i] = mnc0; }
        P.mnc_start[0] = 0;
        P.mnc_start[1] = m0q; P.mnc_start[2] = m0q; P.mnc_start[3] = m0q; P.mnc_start[4] = m0q;
        for (int i = 0; i < 10; ++i) {
            P.pj.W[i] = W_in; P.pj.Wp[i] = Wp_in;
            P.pj.cin[i] = 16; P.pj.cout[i] = 32; P.pj.kvol[i] = KVOL;
        }
        P.pj.start[0] = 0;
        for (int i = 1; i <= 10; ++i) P.pj.start[i] = sz_in;
        P.n_pack = sz_in;
        P.zp = (int*)zp;
        const int total = P.n_cvt + m0q + sz_in;
        prep_all_kernel<<<(total + 255) / 256, 256, 0, stream>>>(P);
    }

    // --- dual: conv_input (blocks [0,gc)) + prep_b (rest) ---
    {
        PrepArgs B;
        B.feat = nullptr; B.featb = nullptr; B.n_cvt = 0;
        const int* nbs[3] = {nbr1, nbr_down, nbr_up};
        const int* mks[3] = {mask1, mask_down, mask_up};
        int* mns[3] = {mnc1, mncd, mncu};
        const int szs4[3] = {KVOL * N1 / 4, KVOL * N1 / 4, KVOL * N0 / 4};
        int macc = 0;
        for (int i = 0; i < 3; ++i) {
            B.nbr[i] = nbs[i]; B.mask[i] = mks[i]; B.mnc[i] = mns[i];
            B.mnc_start[i] = macc; macc += szs4[i];
        }
        B.nbr[3] = nbr_up; B.mask[3] = mask_up; B.mnc[3] = mncu;  // unused slot
        B.mnc_start[3] = macc; B.mnc_start[4] = macc;

        const float* Ws[9] = {W_enc1, W_down, W_enc2, W_lat2, W_up2, W_lat1, W_up1, W_merge2, W_merge1};
        bf16* Wps[9] = {Wp_enc1, Wp_down, Wp_enc2, Wp_lat2, Wp_up2, Wp_lat1, Wp_up1, Wmp2, Wmp1};
        const int cins[9]  = {32, 32, 64, 64, 64, 32, 32, 128, 64};
        const int couts[9] = {32, 64, 64, 64, 32, 32, 32, 64, 32};
        const int kvs[9]   = {KVOL, KVOL, KVOL, KVOL, KVOL, KVOL, KVOL, 1, 1};
        const int szs[9]   = {sz_enc1, sz_down, sz_enc2, sz_lat2, sz_up2, sz_lat1, sz_up1, sz_wm2, sz_wm1};
        int acc = 0;
        for (int i = 0; i < 9; ++i) {
            B.pj.W[i] = Ws[i]; B.pj.Wp[i] = Wps[i];
            B.pj.cin[i] = cins[i]; B.pj.cout[i] = couts[i]; B.pj.kvol[i] = kvs[i];
            B.pj.start[i] = acc; acc += szs[i];
        }
        B.pj.W[9] = W_merge1; B.pj.Wp[9] = Wmp1;   // unused slot
        B.pj.cin[9] = 64; B.pj.cout[9] = 32; B.pj.kvol[9] = 1;
        B.pj.start[9] = acc; B.pj.start[10] = acc;
        B.n_pack = acc;
        B.zp = (int*)zp;

        const int gc = (N0 + 127) / 128;                      // conv_input blocks
        const int gp = (macc + acc + 255) / 256;              // prep_b blocks
        conv_prepb_kernel<16, 32, 2, 4, 2, 3, 4, 2, false>
            <<<gc + gp, 256, 0, stream>>>(featb, Wp_in, mnc0, zp, x0, N0, B, gc);
    }

    launch_conv<32, 32, 2, 4, 2, 3, 4, 2, false>(x0, Wp_enc1, mnc0, zp, e1, N0, stream);

    {
        // down: CIN32/COUT64/CTW2/RT1/WPB4/D3/BR4 -> CTG=2, BROWS=64
        const int g_down = ((N1 + 63) / 64) * 2;
        // lat1: CIN32/COUT32/CTW2/RT4/WPB2/D3/BR4 -> CTG=1, BROWS=128
        const int g_lat1 = (N0 + 127) / 128;
        conv_dual_kernel<32, 64, 2, 1, 4, 3, 4, false,
                         32, 32, 2, 4, 2, 3, 4, false, 2>
            <<<g_down + g_lat1, 256, 0, stream>>>(
                e1, Wp_down, mncd, xd, N1,
                e1, Wp_lat1, mnc0, xl1, N0,
                zp, g_down);
    }

    launch_conv<64, 64, 2, 2, 2, 3, 4, 1, false>(xd, Wp_enc2, mnc1, zp, e2, N1, stream);

    {
        // lat2 + fused merge2: block covers 32 rows x all 64 cols
        const int RG = (N1 + 31) / 32;
        conv_async_kernel<64, 64, 2, 2, 2, 3, 4, 1, false, 2>
            <<<RG, 128, 0, stream>>>(e2, Wp_lat2, mnc1, zp, m2, N1, nullptr, Wmp2);
    }

    {
        // up2 + fused merge1: writes m1 directly (u2 never hits global)
        constexpr int BROWS = 2 * 2 * 16;   // WPB*RT*16 = 64
        const int RG = (N0 + BROWS - 1) / BROWS;
        conv_async_kernel<64, 32, 2, 2, 2, 2, 4, 2, false, 1>
            <<<RG, 128, 0, stream>>>(m2, Wp_up2, mncu, zp, m1, N0, xl1, Wmp1);
    }

    launch_conv<32, 32, 2, 4, 2, 3, 4, 2, true>(m1, Wp_up1, mnc0, zp, (float*)d_out, N0, stream);
}